// Round 10
// baseline (905.666 us; speedup 1.0000x reference)
//
#include <hip/hip_runtime.h>
#include <hip/hip_bf16.h>

typedef __attribute__((ext_vector_type(8))) short bf16x8;
typedef __attribute__((ext_vector_type(4))) float f32x4;

#define DEVI __device__ __forceinline__

DEVI unsigned short f2bf_bits(float f) {
    __hip_bfloat16 h = __float2bfloat16(f);
    return *reinterpret_cast<unsigned short*>(&h);
}
DEVI float bfbits2f(unsigned short u) {
    __hip_bfloat16 h = *reinterpret_cast<__hip_bfloat16*>(&u);
    return __bfloat162float(h);
}

// async global->LDS, 16B per lane. LDS dest is wave-uniform base + lane*16 (linear).
DEVI void gload_lds16(const void* g, void* lds) {
    __builtin_amdgcn_global_load_lds(
        (const __attribute__((address_space(1))) unsigned int*)g,
        (__attribute__((address_space(3))) unsigned int*)lds, 16, 0, 0);
}

template <int N> DEVI void wait_vm() {
    if constexpr (N == 0) asm volatile("s_waitcnt vmcnt(0)" ::: "memory");
    else if constexpr (N == 6) asm volatile("s_waitcnt vmcnt(6)" ::: "memory");
    else if constexpr (N == 12) asm volatile("s_waitcnt vmcnt(12)" ::: "memory");
    __builtin_amdgcn_sched_barrier(0);
}
DEVI void lgkm0() {
    asm volatile("s_waitcnt lgkmcnt(0)" ::: "memory");
    __builtin_amdgcn_sched_barrier(0);
}

// bijective XCD chunking (m204) + group-of-4-rows locality (requires nrow%4==0)
DEVI int2 remap2d(int bid, int total, int gx) {
    int q = total >> 3, r = total & 7, x = bid & 7, l = bid >> 3;
    int seq = (x < r ? x * (q + 1) : r * (q + 1) + (x - r) * q) + l;
    int g4 = seq / (4 * gx);
    int rem = seq - g4 * 4 * gx;
    return {g4 * 4 + (rem & 3), rem >> 2};   // (by, bx)
}

// ---------------- patchify: x[B,C,384,384] -> patches bf16 [4608][1536] (c-major patch dim) ----
__global__ __launch_bounds__(256) void patchify_kernel(const float* __restrict__ x,
                                                       unsigned short* __restrict__ patches)
{
    size_t t8 = (size_t)blockIdx.x * 256 + threadIdx.x;   // 884,736 threads, 8 floats each
    int jq = (int)(t8 % 48);
    size_t t = t8 / 48;
    int r = (int)(t % 384); t /= 384;
    int c = (int)(t % 6);
    int b = (int)(t / 6);
    int j = jq * 8;
    int gh = r >> 4, p1 = r & 15, gw = j >> 4, p2 = j & 15;
    int prow = b * 576 + gh * 24 + gw;
    int pcol = c * 256 + p1 * 16 + p2;
    const float* src = x + ((((size_t)b * 6 + c) * 384 + r) * 384 + j);
    float4 v0 = ((const float4*)src)[0];
    float4 v1 = ((const float4*)src)[1];
    ushort u[8] = { f2bf_bits(v0.x), f2bf_bits(v0.y), f2bf_bits(v0.z), f2bf_bits(v0.w),
                    f2bf_bits(v1.x), f2bf_bits(v1.y), f2bf_bits(v1.z), f2bf_bits(v1.w) };
    *(int4*)&patches[(size_t)prow * 1536 + pcol] = *(int4*)u;
}

// ---------------- patch-weight convert: W f32 [1536][768] -> Wt bf16 [768][1536'] (k-permuted) --
__global__ __launch_bounds__(256) void convT_patch_kernel(const float* __restrict__ W,
                                                          __hip_bfloat16* __restrict__ Wt)
{
    __shared__ float tile[32][33];
    int n0 = blockIdx.x * 32, kp0 = blockIdx.y * 32;
    int tx = threadIdx.x & 31, ty = threadIdx.x >> 5;
#pragma unroll
    for (int i = 0; i < 4; i++) {
        int kp = kp0 + ty + 8 * i;
        int k = (kp & 255) * 6 + (kp >> 8);   // inverse of k' = c*256 + pp
        tile[ty + 8 * i][tx] = W[(size_t)k * 768 + n0 + tx];
    }
    __syncthreads();
#pragma unroll
    for (int i = 0; i < 4; i++)
        Wt[(size_t)(n0 + ty + 8 * i) * 1536 + kp0 + tx] = __float2bfloat16(tile[tx][ty + 8 * i]);
}

// ---------------- weight convert + transpose: W f32 [K][N] -> Wt bf16 [N][K] ----------------
DEVI void convT_body(const float* __restrict__ W, __hip_bfloat16* __restrict__ Wt,
                     int K, int N, int k0, int n0, int tid)
{
    __shared__ float tile[32][33];
    int tx = tid & 31, ty = tid >> 5;
#pragma unroll
    for (int i = 0; i < 4; i++)
        tile[ty + 8 * i][tx] = W[(size_t)(k0 + ty + 8 * i) * N + n0 + tx];
    __syncthreads();
#pragma unroll
    for (int i = 0; i < 4; i++)
        Wt[(size_t)(n0 + ty + 8 * i) * K + k0 + tx] = __float2bfloat16(tile[tx][ty + 8 * i]);
}

DEVI void convT4_dispatch(int bt, const float* wqkv, const float* wout,
                          const float* w1, const float* w2,
                          __hip_bfloat16* dst, int tid)
{
    const float* W; __hip_bfloat16* Wt; int K, N, lt;
    if (bt < 1728)      { W = wqkv; K = 768;  N = 2304; lt = bt;        Wt = dst; }
    else if (bt < 2304) { W = wout; K = 768;  N = 768;  lt = bt - 1728; Wt = dst + 1769472; }
    else if (bt < 4608) { W = w1;   K = 768;  N = 3072; lt = bt - 2304; Wt = dst + 2359296; }
    else                { W = w2;   K = 3072; N = 768;  lt = bt - 4608; Wt = dst + 4718592; }
    int tn = N >> 5;
    convT_body(W, Wt, K, N, (lt / tn) * 32, (lt % tn) * 32, tid);
}

__global__ __launch_bounds__(256) void convT4_kernel(const float* __restrict__ wqkv,
                                                     const float* __restrict__ wout,
                                                     const float* __restrict__ w1,
                                                     const float* __restrict__ w2,
                                                     __hip_bfloat16* __restrict__ dst)
{
    convT4_dispatch(blockIdx.x, wqkv, wout, w1, w2, dst, threadIdx.x);
}

// all 4 layers in one dispatch (grid 27648)
__global__ __launch_bounds__(256) void convT4all_kernel(const float* __restrict__ wqkv,
                                                        const float* __restrict__ wout,
                                                        const float* __restrict__ w1,
                                                        const float* __restrict__ w2,
                                                        __hip_bfloat16* __restrict__ dst)
{
    int l = blockIdx.x / 6912, bt = blockIdx.x % 6912;
    convT4_dispatch(bt,
                    wqkv + (size_t)l * 768 * 2304, wout + (size_t)l * 768 * 768,
                    w1 + (size_t)l * 768 * 3072, w2 + (size_t)l * 3072 * 768,
                    dst + (size_t)l * 7077888, threadIdx.x);
}

// ---------------- layernorm over 768 cols, 192 threads x 4 cols, vectorized ----------------
DEVI void ld4(const float* p, float* v) {
    float4 t = *(const float4*)p; v[0] = t.x; v[1] = t.y; v[2] = t.z; v[3] = t.w;
}
DEVI void ld4(const __hip_bfloat16* p, float* v) {
    ushort4 t = *(const ushort4*)p;
    v[0] = bfbits2f(t.x); v[1] = bfbits2f(t.y); v[2] = bfbits2f(t.z); v[3] = bfbits2f(t.w);
}
DEVI void st4(float* p, const float* v) { *(float4*)p = make_float4(v[0], v[1], v[2], v[3]); }
DEVI void st4(__hip_bfloat16* p, const float* v) {
    ushort4 t = { f2bf_bits(v[0]), f2bf_bits(v[1]), f2bf_bits(v[2]), f2bf_bits(v[3]) };
    *(ushort4*)p = t;
}

template <typename InT, typename OutT>
__global__ __launch_bounds__(192) void ln_kernel(const InT* __restrict__ x,
                                                 const float* __restrict__ g,
                                                 const float* __restrict__ b,
                                                 OutT* __restrict__ out)
{
    int row = blockIdx.x, tid = threadIdx.x;   // 192 threads * 4 cols = 768
    float v[4], gv[4], bv[4];
    ld4(&x[(size_t)row * 768 + tid * 4], v);
    float s = v[0] + v[1] + v[2] + v[3];
    float s2 = v[0] * v[0] + v[1] * v[1] + v[2] * v[2] + v[3] * v[3];
#pragma unroll
    for (int m = 32; m >= 1; m >>= 1) { s += __shfl_xor(s, m); s2 += __shfl_xor(s2, m); }
    __shared__ float red[6];
    int w = tid >> 6;
    if ((tid & 63) == 0) { red[w] = s; red[3 + w] = s2; }
    __syncthreads();
    s = red[0] + red[1] + red[2];
    s2 = red[3] + red[4] + red[5];
    float mean = s * (1.0f / 768.0f);
    float var = s2 * (1.0f / 768.0f) - mean * mean;
    float rstd = rsqrtf(var + 1e-5f);
    ld4(&g[tid * 4], gv);
    ld4(&b[tid * 4], bv);
    float o[4];
#pragma unroll
    for (int i = 0; i < 4; i++) o[i] = (v[i] - mean) * rstd * gv[i] + bv[i];
    st4(&out[(size_t)row * 768 + tid * 4], o);
}

// ---------------- narrow GEMM: BM=64 x BN=128, BK=64, 3-deep counted-vmcnt, bf16 out ----------
// 2 blocks/CU (74 KB LDS); independent-block TLP hides staging latency. Chunk swizzle:
// phys p of row r holds logical chunk p ^ (r&7) (applied on per-lane GLOBAL source; gload
// dest linear; ds_read XORs the chunk position).
template <bool BIAS, bool RESID, bool GELU>
__global__ __launch_bounds__(256, 2) void gemm_bt_kernel(
    const __hip_bfloat16* __restrict__ A,
    const __hip_bfloat16* __restrict__ Bt,
    const float* __restrict__ bias,
    const __hip_bfloat16* __restrict__ resid,
    __hip_bfloat16* __restrict__ Cb,
    int M, int N, int K, int gx)
{
    constexpr int BM = 64, SL = 6;
    __shared__ __align__(16) __hip_bfloat16 As[3][BM * 64];
    __shared__ __align__(16) __hip_bfloat16 Bs[3][128 * 64];
    const int tid = threadIdx.x;
    const int wid = tid >> 6, lane = tid & 63;
    const int g = lane >> 4, l16 = lane & 15;
    const int wm = (wid >> 1) * 32, wn = (wid & 1) * 64;

    int2 bc = remap2d(blockIdx.x, gridDim.x, gx);
    const int bm = bc.x * BM, bn = bc.y * 128;

    const int sr32 = tid >> 3, ci = tid & 7;
    const int cg = ci ^ (sr32 & 7);
    const int sdst = tid * 8;
    size_t aOff[2], bOff[4];
#pragma unroll
    for (int i = 0; i < 2; i++) aOff[i] = (size_t)(bm + i * 32 + sr32) * K + cg * 8;
#pragma unroll
    for (int i = 0; i < 4; i++) bOff[i] = (size_t)(bn + i * 32 + sr32) * K + cg * 8;

    auto stage = [&](__hip_bfloat16* asb, __hip_bfloat16* bsb, int tq) {
        const __hip_bfloat16* ap = A + tq * 64;
        const __hip_bfloat16* bp = Bt + tq * 64;
#pragma unroll
        for (int i = 0; i < 2; i++) gload_lds16(ap + aOff[i], asb + i * 2048 + sdst);
#pragma unroll
        for (int i = 0; i < 4; i++) gload_lds16(bp + bOff[i], bsb + i * 2048 + sdst);
    };

    f32x4 acc[2][4] = {};
    const int nt = K >> 6;   // 12 / 24 / 48 — all divisible by 3

    stage(As[0], Bs[0], 0);
    stage(As[1], Bs[1], 1);
    stage(As[2], Bs[2], 2);
    wait_vm<12>();
    __builtin_amdgcn_s_barrier();
    __builtin_amdgcn_sched_barrier(0);

    for (int t = 0; t < nt; t += 3) {
#pragma unroll
        for (int u = 0; u < 3; u++) {
            const int tc = t + u;
            bf16x8 af[2][2], bfr[2][4];
#pragma unroll
            for (int s = 0; s < 2; s++) {
                const int cp = ((s * 4 + g) ^ (l16 & 7)) << 3;
#pragma unroll
                for (int mi = 0; mi < 2; mi++)
                    af[s][mi] = *(const bf16x8*)&As[u][(wm + mi * 16 + l16) * 64 + cp];
#pragma unroll
                for (int ni = 0; ni < 4; ni++)
                    bfr[s][ni] = *(const bf16x8*)&Bs[u][(wn + ni * 16 + l16) * 64 + cp];
            }
#pragma unroll
            for (int s = 0; s < 2; s++)
#pragma unroll
                for (int mi = 0; mi < 2; mi++)
#pragma unroll
                    for (int ni = 0; ni < 4; ni++)
                        acc[mi][ni] = __builtin_amdgcn_mfma_f32_16x16x32_bf16(af[s][mi], bfr[s][ni], acc[mi][ni], 0, 0, 0);

            lgkm0();
            __builtin_amdgcn_s_barrier();
            __builtin_amdgcn_sched_barrier(0);

            if (tc + 3 < nt) stage(As[u], Bs[u], tc + 3);
            if (tc + 1 < nt) {
                if (tc + 4 <= nt)      wait_vm<12>();
                else if (tc + 3 == nt) wait_vm<6>();
                else                   wait_vm<0>();
                __builtin_amdgcn_s_barrier();
                __builtin_amdgcn_sched_barrier(0);
            }
        }
    }

    // epilogue: per-wave LDS transpose (scratch in As), coalesced 16B stores
    __hip_bfloat16* scr = &As[0][0] + wid * (16 * 72);
#pragma unroll
    for (int mi = 0; mi < 2; mi++) {
#pragma unroll
        for (int ni = 0; ni < 4; ni++) {
            float bval = 0.0f;
            if (BIAS) bval = bias[bn + wn + ni * 16 + l16];
#pragma unroll
            for (int r = 0; r < 4; r++) {
                float v = acc[mi][ni][r] + bval;
                if (GELU) v = 0.5f * v * (1.0f + erff(v * 0.70710678118654752f));
                scr[(4 * g + r) * 72 + ni * 16 + l16] = __float2bfloat16(v);
            }
        }
        lgkm0();
#pragma unroll
        for (int q2 = 0; q2 < 2; q2++) {
            int row16 = q2 * 8 + (lane >> 3), ch = lane & 7;
            bf16x8 vv = *(const bf16x8*)&scr[row16 * 72 + ch * 8];
            int grow = bm + wm + mi * 16 + row16;
            size_t off = (size_t)grow * N + bn + wn + ch * 8;
            if (RESID) {
                bf16x8 rv = *(const bf16x8*)&resid[off];
#pragma unroll
                for (int e = 0; e < 8; e++)
                    vv[e] = (short)f2bf_bits(bfbits2f((unsigned short)vv[e]) + bfbits2f((unsigned short)rv[e]));
            }
            *(int4*)&Cb[off] = *(int4*)&vv;
        }
        lgkm0();
    }
}

// ---------------- MFMA flash attention: softmax(q@k^T*scale + bias) @ v ----------------
__global__ __launch_bounds__(256) void attn_kernel(const __hip_bfloat16* __restrict__ qkvb,
                                                   const float* __restrict__ bias,   // [12][576][576] this layer
                                                   unsigned short* __restrict__ o)   // bf16 [4608][768]
{
    const int seq = (blockIdx.x & 7) * 108 + (blockIdx.x >> 3);
    const int bb = seq & 7, qt = (seq >> 3) % 9, h = seq / 72;
    const int q0 = qt * 64;
    const int tid = threadIdx.x;
    const int wq = tid >> 6, lane = tid & 63, g = lane >> 4, l16 = lane & 15;

    __shared__ __align__(16) unsigned short Qs[64 * 72];
    __shared__ __align__(16) unsigned short Ks[64 * 72];
    __shared__ __align__(16) unsigned short Vt[64 * 72];
    __shared__ __align__(16) unsigned short Ps[4][16 * 72];

    {
        int r = tid >> 2, cb = (tid & 3) * 16;
        const int4* s4 = (const int4*)&qkvb[(size_t)(bb * 576 + q0 + r) * 2304 + h * 64 + cb];
        int4* d4 = (int4*)&Qs[r * 72 + cb];
        d4[0] = s4[0]; d4[1] = s4[1];
    }
    __syncthreads();
    bf16x8 qf0 = *(const bf16x8*)&Qs[(wq * 16 + l16) * 72 + g * 8];
    bf16x8 qf1 = *(const bf16x8*)&Qs[(wq * 16 + l16) * 72 + 32 + g * 8];

    float m_r[4] = {-1e30f, -1e30f, -1e30f, -1e30f};
    float l_r[4] = {0.f, 0.f, 0.f, 0.f};
    f32x4 oa[4] = {};
    const float* bias_h = bias + (size_t)h * 576 * 576;
    const float scale = 0.125f;

    for (int kt = 0; kt < 576; kt += 64) {
        {
            int r = tid >> 2, cb = (tid & 3) * 16;
            const int4* s4 = (const int4*)&qkvb[(size_t)(bb * 576 + kt + r) * 2304 + 768 + h * 64 + cb];
            int4* d4 = (int4*)&Ks[r * 72 + cb];
            d4[0] = s4[0]; d4[1] = s4[1];
            int key = tid & 63, d0 = (tid >> 6) * 16;
            const unsigned short* vs = (const unsigned short*)&qkvb[(size_t)(bb * 576 + kt + key) * 2304 + 1536 + h * 64 + d0];
            bf16x8 v0 = *(const bf16x8*)vs;
            bf16x8 v1 = *(const bf16x8*)(vs + 8);
#pragma unroll
            for (int e = 0; e < 8; e++) {
                Vt[(d0 + e) * 72 + key] = (unsigned short)v0[e];
                Vt[(d0 + 8 + e) * 72 + key] = (unsigned short)v1[e];
            }
        }
        __syncthreads();

        float bl[4][4];
#pragma unroll
        for (int kc = 0; kc < 4; kc++)
#pragma unroll
            for (int r = 0; r < 4; r++) {
                int q = q0 + wq * 16 + 4 * g + r;
                bl[kc][r] = bias_h[(size_t)q * 576 + kt + kc * 16 + l16];
            }

        f32x4 sc[4] = {};
        __builtin_amdgcn_s_setprio(1);
#pragma unroll
        for (int kc = 0; kc < 4; kc++) {
            bf16x8 kf0 = *(const bf16x8*)&Ks[(kc * 16 + l16) * 72 + g * 8];
            bf16x8 kf1 = *(const bf16x8*)&Ks[(kc * 16 + l16) * 72 + 32 + g * 8];
            sc[kc] = __builtin_amdgcn_mfma_f32_16x16x32_bf16(qf0, kf0, sc[kc], 0, 0, 0);
            sc[kc] = __builtin_amdgcn_mfma_f32_16x16x32_bf16(qf1, kf1, sc[kc], 0, 0, 0);
        }
        __builtin_amdgcn_s_setprio(0);

        float sv[4][4], mt[4] = {-1e30f, -1e30f, -1e30f, -1e30f};
#pragma unroll
        for (int kc = 0; kc < 4; kc++)
#pragma unroll
            for (int r = 0; r < 4; r++) {
                float s = sc[kc][r] * scale + bl[kc][r];
                sv[kc][r] = s;
                mt[r] = fmaxf(mt[r], s);
            }
#pragma unroll
        for (int r = 0; r < 4; r++)
#pragma unroll
            for (int m = 1; m < 16; m <<= 1) mt[r] = fmaxf(mt[r], __shfl_xor(mt[r], m));

        float sf[4];
#pragma unroll
        for (int r = 0; r < 4; r++) {
            float mn = fmaxf(m_r[r], mt[r]);
            sf[r] = __expf(m_r[r] - mn);
            m_r[r] = mn;
        }
        float rs[4] = {0.f, 0.f, 0.f, 0.f};
#pragma unroll
        for (int kc = 0; kc < 4; kc++)
#pragma unroll
            for (int r = 0; r < 4; r++) {
                float p = __expf(sv[kc][r] - m_r[r]);
                rs[r] += p;
                Ps[wq][(4 * g + r) * 72 + kc * 16 + l16] = f2bf_bits(p);
            }
#pragma unroll
        for (int r = 0; r < 4; r++) {
#pragma unroll
            for (int m = 1; m < 16; m <<= 1) rs[r] += __shfl_xor(rs[r], m);
            l_r[r] = l_r[r] * sf[r] + rs[r];
        }
#pragma unroll
        for (int dt = 0; dt < 4; dt++)
#pragma unroll
            for (int r = 0; r < 4; r++) oa[dt][r] *= sf[r];

        asm volatile("s_waitcnt lgkmcnt(0)" ::: "memory");

        __builtin_amdgcn_s_setprio(1);
#pragma unroll
        for (int s = 0; s < 2; s++) {
            bf16x8 pf = *(const bf16x8*)&Ps[wq][l16 * 72 + s * 32 + g * 8];
#pragma unroll
            for (int dt = 0; dt < 4; dt++) {
                bf16x8 vf = *(const bf16x8*)&Vt[(dt * 16 + l16) * 72 + s * 32 + g * 8];
                oa[dt] = __builtin_amdgcn_mfma_f32_16x16x32_bf16(pf, vf, oa[dt], 0, 0, 0);
            }
        }
        __builtin_amdgcn_s_setprio(0);
        __syncthreads();
    }

#pragma unroll
    for (int dt = 0; dt < 4; dt++)
#pragma unroll
        for (int r = 0; r < 4; r++) {
            int q = q0 + wq * 16 + 4 * g + r;
            float v = oa[dt][r] / l_r[r];
            o[(size_t)(bb * 576 + q) * 768 + h * 64 + dt * 16 + l16] = f2bf_bits(v);
        }
}

// ---------------- mean pool over 576 tokens (bf16 in) ----------------
__global__ __launch_bounds__(256) void pool_kernel(const __hip_bfloat16* __restrict__ tok,
                                                   float* __restrict__ pooled)
{
    int d = blockIdx.x * 256 + threadIdx.x;
    int b = blockIdx.y;
    float s = 0.0f;
    for (int n = 0; n < 576; n++) s += __bfloat162float(tok[(size_t)(b * 576 + n) * 768 + d]);
    pooled[b * 768 + d] = s * (1.0f / 576.0f);
}

// ---------------- classifier head ----------------
__global__ __launch_bounds__(256) void head_kernel(const float* __restrict__ lnp,
                                                   const float* __restrict__ w,
                                                   const float* __restrict__ bh,
                                                   float* __restrict__ out)
{
    int c = blockIdx.x * 256 + threadIdx.x;
    int b = blockIdx.y;
    if (c >= 1000) return;
    float s = bh[c];
    for (int d = 0; d < 768; d++) s += lnp[b * 768 + d] * w[(size_t)d * 1000 + c];
    out[b * 1000 + c] = s;
}

extern "C" void kernel_launch(void* const* d_in, const int* in_sizes, int n_in,
                              void* d_out, int out_size, void* d_ws, size_t ws_size,
                              hipStream_t stream)
{
    const float* x = (const float*)d_in[0];
    const float* patch_w = (const float*)d_in[1];
    const float* patch_b = (const float*)d_in[2];
    const float* ln1_g = (const float*)d_in[3];
    const float* ln1_b = (const float*)d_in[4];
    const float* w_qkv = (const float*)d_in[5];
    const float* bias_att = (const float*)d_in[6];
    const float* w_out = (const float*)d_in[7];
    const float* ln2_g = (const float*)d_in[8];
    const float* ln2_b = (const float*)d_in[9];
    const float* w1 = (const float*)d_in[10];
    const float* b1 = (const float*)d_in[11];
    const float* w2 = (const float*)d_in[12];
    const float* b2 = (const float*)d_in[13];
    const float* lnh_g = (const float*)d_in[14];
    const float* lnh_b = (const float*)d_in[15];
    const float* w_head = (const float*)d_in[16];
    const float* b_head = (const float*)d_in[17];
    float* out = (float*)d_out;

    char* ws = (char*)d_ws;
    __hip_bfloat16* tok = (__hip_bfloat16*)(ws + 0);             // 4608*768 bf16
    __hip_bfloat16* qkv_bf = (__hip_bfloat16*)(ws + 14155776);   // 4608*2304 bf16
    float* pooled = (float*)(ws + 56623104);
    float* pooledln = (float*)(ws + 56647680);
    __hip_bfloat16* patches = (__hip_bfloat16*)(ws + 56672256);  // 4608*1536 bf16
    __hip_bfloat16* lw = patches;                                // per-layer weights (fallback path)
    __hip_bfloat16* h_bf = (__hip_bfloat16*)(ws + 70828032);
    __hip_bfloat16* o_bf = (__hip_bfloat16*)(ws + 77905920);
    __hip_bfloat16* hid_bf = (__hip_bfloat16*)(ws + 84983808);
    __hip_bfloat16* wbuf = (__hip_bfloat16*)(ws + 113295360);    // patch weight 768*1536 bf16
    __hip_bfloat16* lwAll = (__hip_bfloat16*)(ws + 118013952);   // all-layers weights (gated)
    const bool useAll = ws_size >= (size_t)118013952 + 56623104; // 174,637,056 B

    // patch embedding
    patchify_kernel<<<3456, 256, 0, stream>>>(x, (unsigned short*)patches);
    convT_patch_kernel<<<dim3(24, 48), 256, 0, stream>>>(patch_w, wbuf);
    gemm_bt_kernel<true, false, false><<<432, 256, 0, stream>>>(
        patches, wbuf, patch_b, nullptr, tok, 4608, 768, 1536, 6);

    if (useAll)
        convT4all_kernel<<<27648, 256, 0, stream>>>(w_qkv, w_out, w1, w2, lwAll);

    for (int l = 0; l < 4; l++) {
        __hip_bfloat16* lwl = useAll ? lwAll + (size_t)l * 7077888 : lw;
        if (!useAll)
            convT4_kernel<<<6912, 256, 0, stream>>>(
                w_qkv + (size_t)l * 768 * 2304, w_out + (size_t)l * 768 * 768,
                w1 + (size_t)l * 768 * 3072, w2 + (size_t)l * 3072 * 768, lw);
        // attn sub-block
        ln_kernel<__hip_bfloat16, __hip_bfloat16><<<4608, 192, 0, stream>>>(
            tok, ln1_g + l * 768, ln1_b + l * 768, h_bf);
        gemm_bt_kernel<false, false, false><<<1296, 256, 0, stream>>>(
            h_bf, lwl, nullptr, nullptr, qkv_bf, 4608, 2304, 768, 18);
        attn_kernel<<<864, 256, 0, stream>>>(
            qkv_bf, bias_att + (size_t)l * 12 * 576 * 576, (unsigned short*)o_bf);
        gemm_bt_kernel<false, true, false><<<432, 256, 0, stream>>>(
            o_bf, lwl + 1769472, nullptr, tok, tok, 4608, 768, 768, 6);
        // mlp sub-block
        ln_kernel<__hip_bfloat16, __hip_bfloat16><<<4608, 192, 0, stream>>>(
            tok, ln2_g + l * 768, ln2_b + l * 768, h_bf);
        gemm_bt_kernel<true, false, true><<<1728, 256, 0, stream>>>(
            h_bf, lwl + 2359296, b1 + l * 3072, nullptr, hid_bf, 4608, 3072, 768, 24);
        gemm_bt_kernel<true, true, false><<<432, 256, 0, stream>>>(
            hid_bf, lwl + 4718592, b2 + l * 768, tok, tok, 4608, 768, 3072, 6);
    }

    pool_kernel<<<dim3(3, 8), 256, 0, stream>>>(tok, pooled);
    ln_kernel<float, float><<<8, 192, 0, stream>>>(pooled, lnh_g, lnh_b, pooledln);
    head_kernel<<<dim3(4, 8), 256, 0, stream>>>(pooledln, w_head, b_head, out);
}

// Round 11
// 900.425 us; speedup vs baseline: 1.0058x; 1.0058x over previous
//
#include <hip/hip_runtime.h>
#include <hip/hip_bf16.h>

typedef __attribute__((ext_vector_type(8))) short bf16x8;
typedef __attribute__((ext_vector_type(4))) float f32x4;

#define DEVI __device__ __forceinline__

DEVI unsigned short f2bf_bits(float f) {
    __hip_bfloat16 h = __float2bfloat16(f);
    return *reinterpret_cast<unsigned short*>(&h);
}
DEVI float bfbits2f(unsigned short u) {
    __hip_bfloat16 h = *reinterpret_cast<__hip_bfloat16*>(&u);
    return __bfloat162float(h);
}

// async global->LDS, 16B per lane. LDS dest is wave-uniform base + lane*16 (linear).
DEVI void gload_lds16(const void* g, void* lds) {
    __builtin_amdgcn_global_load_lds(
        (const __attribute__((address_space(1))) unsigned int*)g,
        (__attribute__((address_space(3))) unsigned int*)lds, 16, 0, 0);
}

template <int N> DEVI void wait_vm() {
    if constexpr (N == 0) asm volatile("s_waitcnt vmcnt(0)" ::: "memory");
    else if constexpr (N == 4) asm volatile("s_waitcnt vmcnt(4)" ::: "memory");
    else if constexpr (N == 6) asm volatile("s_waitcnt vmcnt(6)" ::: "memory");
    else if constexpr (N == 12) asm volatile("s_waitcnt vmcnt(12)" ::: "memory");
    __builtin_amdgcn_sched_barrier(0);
}
DEVI void lgkm0() {
    asm volatile("s_waitcnt lgkmcnt(0)" ::: "memory");
    __builtin_amdgcn_sched_barrier(0);
}

// bijective XCD chunking (m204) + group-of-4-rows locality (requires nrow%4==0)
DEVI int2 remap2d(int bid, int total, int gx) {
    int q = total >> 3, r = total & 7, x = bid & 7, l = bid >> 3;
    int seq = (x < r ? x * (q + 1) : r * (q + 1) + (x - r) * q) + l;
    int g4 = seq / (4 * gx);
    int rem = seq - g4 * 4 * gx;
    return {g4 * 4 + (rem & 3), rem >> 2};   // (by, bx)
}
// group-of-2 variant — used by 256-tile kernels
DEVI int2 remap2d_g2(int bid, int total, int gx) {
    int q = total >> 3, r = total & 7, x = bid & 7, l = bid >> 3;
    int seq = (x < r ? x * (q + 1) : r * (q + 1) + (x - r) * q) + l;
    int g2 = seq / (2 * gx);
    int rem = seq - g2 * 2 * gx;
    return {g2 * 2 + (rem & 1), rem >> 1};
}

// ---------------- patchify: x[B,C,384,384] -> patches bf16 [4608][1536] (c-major patch dim) ----
__global__ __launch_bounds__(256) void patchify_kernel(const float* __restrict__ x,
                                                       unsigned short* __restrict__ patches)
{
    size_t t8 = (size_t)blockIdx.x * 256 + threadIdx.x;   // 884,736 threads, 8 floats each
    int jq = (int)(t8 % 48);
    size_t t = t8 / 48;
    int r = (int)(t % 384); t /= 384;
    int c = (int)(t % 6);
    int b = (int)(t / 6);
    int j = jq * 8;
    int gh = r >> 4, p1 = r & 15, gw = j >> 4, p2 = j & 15;
    int prow = b * 576 + gh * 24 + gw;
    int pcol = c * 256 + p1 * 16 + p2;
    const float* src = x + ((((size_t)b * 6 + c) * 384 + r) * 384 + j);
    float4 v0 = ((const float4*)src)[0];
    float4 v1 = ((const float4*)src)[1];
    ushort u[8] = { f2bf_bits(v0.x), f2bf_bits(v0.y), f2bf_bits(v0.z), f2bf_bits(v0.w),
                    f2bf_bits(v1.x), f2bf_bits(v1.y), f2bf_bits(v1.z), f2bf_bits(v1.w) };
    *(int4*)&patches[(size_t)prow * 1536 + pcol] = *(int4*)u;
}

// ---------------- patch-weight convert: W f32 [1536][768] -> Wt bf16 [768][1536'] (k-permuted) --
__global__ __launch_bounds__(256) void convT_patch_kernel(const float* __restrict__ W,
                                                          __hip_bfloat16* __restrict__ Wt)
{
    __shared__ float tile[32][33];
    int n0 = blockIdx.x * 32, kp0 = blockIdx.y * 32;
    int tx = threadIdx.x & 31, ty = threadIdx.x >> 5;
#pragma unroll
    for (int i = 0; i < 4; i++) {
        int kp = kp0 + ty + 8 * i;
        int k = (kp & 255) * 6 + (kp >> 8);   // inverse of k' = c*256 + pp
        tile[ty + 8 * i][tx] = W[(size_t)k * 768 + n0 + tx];
    }
    __syncthreads();
#pragma unroll
    for (int i = 0; i < 4; i++)
        Wt[(size_t)(n0 + ty + 8 * i) * 1536 + kp0 + tx] = __float2bfloat16(tile[tx][ty + 8 * i]);
}

// ---------------- weight convert + transpose (+optional per-k scale): W[K][N] -> Wt[N][K] ------
DEVI void convT_body(const float* __restrict__ W, __hip_bfloat16* __restrict__ Wt,
                     const float* __restrict__ gvec,
                     int K, int N, int k0, int n0, int tid)
{
    __shared__ float tile[32][33];
    int tx = tid & 31, ty = tid >> 5;
#pragma unroll
    for (int i = 0; i < 4; i++)
        tile[ty + 8 * i][tx] = W[(size_t)(k0 + ty + 8 * i) * N + n0 + tx];
    __syncthreads();
    float gk = gvec ? gvec[k0 + tx] : 1.0f;
#pragma unroll
    for (int i = 0; i < 4; i++)
        Wt[(size_t)(n0 + ty + 8 * i) * K + k0 + tx] = __float2bfloat16(tile[tx][ty + 8 * i] * gk);
}

// one layer's 4 weights -> lw; qkv gets ln1_g folded, w1 gets ln2_g folded.
DEVI void convT4_dispatch(int bt, const float* wqkv, const float* wout,
                          const float* w1, const float* w2,
                          const float* g1, const float* g2,
                          __hip_bfloat16* dst, int tid)
{
    const float* W; const float* gv = nullptr; __hip_bfloat16* Wt; int K, N, lt;
    if (bt < 1728)      { W = wqkv; K = 768;  N = 2304; lt = bt;        Wt = dst;           gv = g1; }
    else if (bt < 2304) { W = wout; K = 768;  N = 768;  lt = bt - 1728; Wt = dst + 1769472; }
    else if (bt < 4608) { W = w1;   K = 768;  N = 3072; lt = bt - 2304; Wt = dst + 2359296; gv = g2; }
    else                { W = w2;   K = 3072; N = 768;  lt = bt - 4608; Wt = dst + 4718592; }
    int tn = N >> 5;
    convT_body(W, Wt, gv, K, N, (lt / tn) * 32, (lt % tn) * 32, tid);
}

__global__ __launch_bounds__(256) void convT4_kernel(const float* __restrict__ wqkv,
                                                     const float* __restrict__ wout,
                                                     const float* __restrict__ w1,
                                                     const float* __restrict__ w2,
                                                     const float* __restrict__ g1,
                                                     const float* __restrict__ g2,
                                                     __hip_bfloat16* __restrict__ dst)
{
    convT4_dispatch(blockIdx.x, wqkv, wout, w1, w2, g1, g2, dst, threadIdx.x);
}

__global__ __launch_bounds__(256) void convT4all_kernel(const float* __restrict__ wqkv,
                                                        const float* __restrict__ wout,
                                                        const float* __restrict__ w1,
                                                        const float* __restrict__ w2,
                                                        const float* __restrict__ ln1_g,
                                                        const float* __restrict__ ln2_g,
                                                        __hip_bfloat16* __restrict__ dst)
{
    int l = blockIdx.x / 6912, bt = blockIdx.x % 6912;
    convT4_dispatch(bt,
                    wqkv + (size_t)l * 768 * 2304, wout + (size_t)l * 768 * 768,
                    w1 + (size_t)l * 768 * 3072, w2 + (size_t)l * 3072 * 768,
                    ln1_g + l * 768, ln2_g + l * 768,
                    dst + (size_t)l * 7077888, threadIdx.x);
}

// ---------------- LN-fold coefficients: per layer, c2[n]=sum_k g[k]W[k][n], c1[n]=sum_k b[k]W[k][n]
// layout per layer: [c1q 2304][c2q 2304][c1u 3072][c2u 3072] = 10752 f32
__global__ __launch_bounds__(256) void lncoef_kernel(const float* __restrict__ wqkv,
                                                     const float* __restrict__ w1,
                                                     const float* __restrict__ ln1_g,
                                                     const float* __restrict__ ln1_b,
                                                     const float* __restrict__ ln2_g,
                                                     const float* __restrict__ ln2_b,
                                                     const float* __restrict__ b1,
                                                     float* __restrict__ coef)
{
    int l = blockIdx.y;
    int n = blockIdx.x * 256 + threadIdx.x;   // 0..5375
    const float* W; const float* g; const float* b; int N; int n0; float* dst; float extra = 0.f;
    if (n < 2304) { W = wqkv + (size_t)l * 768 * 2304; g = ln1_g + l * 768; b = ln1_b + l * 768;
                    N = 2304; n0 = n; dst = coef + (size_t)l * 10752; }
    else          { W = w1 + (size_t)l * 768 * 3072;   g = ln2_g + l * 768; b = ln2_b + l * 768;
                    N = 3072; n0 = n - 2304; dst = coef + (size_t)l * 10752 + 4608;
                    extra = b1[l * 3072 + n0]; }
    float s1 = 0.f, s2 = 0.f;
    for (int k = 0; k < 768; k++) {
        float w = W[(size_t)k * N + n0];
        s1 += b[k] * w;
        s2 += g[k] * w;
    }
    dst[n0] = s1 + extra;                 // c1 (+b1 for mlp-up)
    dst[(N == 2304 ? 2304 : 3072) + n0] = s2;   // c2
}

// ---------------- per-row mean/rstd of tok: stats[row] = (mu, rstd) ----------------
__global__ __launch_bounds__(256) void stats_kernel(const __hip_bfloat16* __restrict__ tok,
                                                    float2* __restrict__ stats)
{
    int row = blockIdx.x * 4 + (threadIdx.x >> 6);
    int lane = threadIdx.x & 63;
    const unsigned short* tr = (const unsigned short*)(tok + (size_t)row * 768) + lane * 12;
    float s = 0.f, s2 = 0.f;
#pragma unroll
    for (int i = 0; i < 3; i++) {
        ushort4 u = ((const ushort4*)tr)[i];
        float v0 = bfbits2f(u.x), v1 = bfbits2f(u.y), v2 = bfbits2f(u.z), v3 = bfbits2f(u.w);
        s += v0 + v1 + v2 + v3;
        s2 += v0 * v0 + v1 * v1 + v2 * v2 + v3 * v3;
    }
#pragma unroll
    for (int m = 32; m >= 1; m >>= 1) { s += __shfl_xor(s, m); s2 += __shfl_xor(s2, m); }
    if (lane == 0) {
        float mean = s * (1.0f / 768.0f);
        float var = s2 * (1.0f / 768.0f) - mean * mean;
        stats[row] = make_float2(mean, rsqrtf(var + 1e-5f));
    }
}

// ---------------- layernorm (float head path only) ----------------
__global__ __launch_bounds__(192) void lnf_kernel(const float* __restrict__ x,
                                                  const float* __restrict__ g,
                                                  const float* __restrict__ b,
                                                  float* __restrict__ out)
{
    int row = blockIdx.x, tid = threadIdx.x;
    float4 v4 = *(const float4*)&x[(size_t)row * 768 + tid * 4];
    float v[4] = {v4.x, v4.y, v4.z, v4.w};
    float s = v[0] + v[1] + v[2] + v[3];
    float s2 = v[0] * v[0] + v[1] * v[1] + v[2] * v[2] + v[3] * v[3];
#pragma unroll
    for (int m = 32; m >= 1; m >>= 1) { s += __shfl_xor(s, m); s2 += __shfl_xor(s2, m); }
    __shared__ float red[6];
    int w = tid >> 6;
    if ((tid & 63) == 0) { red[w] = s; red[3 + w] = s2; }
    __syncthreads();
    s = red[0] + red[1] + red[2];
    s2 = red[3] + red[4] + red[5];
    float mean = s * (1.0f / 768.0f);
    float var = s2 * (1.0f / 768.0f) - mean * mean;
    float rstd = rsqrtf(var + 1e-5f);
    float4 g4 = *(const float4*)&g[tid * 4];
    float4 b4 = *(const float4*)&b[tid * 4];
    float o[4] = { (v[0] - mean) * rstd * g4.x + b4.x, (v[1] - mean) * rstd * g4.y + b4.y,
                   (v[2] - mean) * rstd * g4.z + b4.z, (v[3] - mean) * rstd * g4.w + b4.w };
    *(float4*)&out[(size_t)row * 768 + tid * 4] = make_float4(o[0], o[1], o[2], o[3]);
}

// ================= 256x256 8-phase GEMM with LN fold: C = LNrow(A) @ (g W)^T via =================
//   C[r][n] = rstd_r * (acc[r][n] - mu_r * c2[n]) + c1[n]   (+gelu)
template <bool GELU>
__global__ __launch_bounds__(512, 2) void gemm_8ph_kernel(
    const __hip_bfloat16* __restrict__ A,
    const __hip_bfloat16* __restrict__ Bt,
    const float2* __restrict__ stats,
    const float* __restrict__ c1v,
    const float* __restrict__ c2v,
    __hip_bfloat16* __restrict__ Cb,
    int M, int N, int K, int gx)
{
    __shared__ __align__(16) __hip_bfloat16 AsF[32768];   // [2][2][256][32]
    __shared__ __align__(16) __hip_bfloat16 BsF[32768];
    const int tid = threadIdx.x;
    const int wid = tid >> 6, lane = tid & 63;
    const int g = lane >> 4, l16 = lane & 15;
    const int wmh = wid >> 2, wnn = wid & 3;

    int2 bc = remap2d_g2(blockIdx.x, gridDim.x, gx);
    const int bm = bc.x * 256, bn = bc.y * 256;

    const int srow = tid >> 2;
    size_t aS[2], bS[2];
#pragma unroll
    for (int i = 0; i < 2; i++) {
        int row = i * 128 + srow;
        int lc = (tid & 3) ^ ((row >> 1) & 3);
        aS[i] = (size_t)(bm + row) * K + lc * 8;
        bS[i] = (size_t)(bn + row) * K + lc * 8;
    }
    auto stageA = [&](int buf, int kh, int tq) {
        const __hip_bfloat16* ap = A + (size_t)tq * 64 + kh * 32;
        __hip_bfloat16* dst = AsF + (buf * 2 + kh) * 8192;
        gload_lds16(ap + aS[0], dst + tid * 8);
        gload_lds16(ap + aS[1], dst + 4096 + tid * 8);
    };
    auto stageB = [&](int buf, int kh, int tq) {
        const __hip_bfloat16* bp = Bt + (size_t)tq * 64 + kh * 32;
        __hip_bfloat16* dst = BsF + (buf * 2 + kh) * 8192;
        gload_lds16(bp + bS[0], dst + tid * 8);
        gload_lds16(bp + bS[1], dst + 4096 + tid * 8);
    };

    const int csw = (l16 >> 1) & 3;
    const int rdo = (g ^ csw) << 3;
    const int aBase = (wmh * 128 + l16) * 32 + rdo;
    const int bBase = (wnn * 64 + l16) * 32 + rdo;

    f32x4 acc[8][4] = {};
    const int nt = K >> 6;

    stageA(0, 0, 0); stageB(0, 0, 0); stageA(0, 1, 0); stageB(0, 1, 0);
    stageA(1, 0, 1); stageB(1, 0, 1);
    wait_vm<4>();
    __builtin_amdgcn_s_barrier();
    __builtin_amdgcn_sched_barrier(0);

    bf16x8 af[8], bf2[2];
    for (int t = 0; t < nt; t++) {
        const int b = t & 1;
        const int k0 = (b * 2 + 0) * 8192, k1 = (b * 2 + 1) * 8192;

#pragma unroll
        for (int mi = 0; mi < 8; mi++) af[mi] = *(const bf16x8*)&AsF[k0 + aBase + mi * 512];
        bf2[0] = *(const bf16x8*)&BsF[k0 + bBase + 0 * 512];
        bf2[1] = *(const bf16x8*)&BsF[k0 + bBase + 1 * 512];
        if (t + 1 < nt) stageA(b ^ 1, 1, t + 1);
        __builtin_amdgcn_s_barrier(); lgkm0();
        __builtin_amdgcn_s_setprio(1);
#pragma unroll
        for (int mi = 0; mi < 8; mi++) {
            acc[mi][0] = __builtin_amdgcn_mfma_f32_16x16x32_bf16(af[mi], bf2[0], acc[mi][0], 0, 0, 0);
            acc[mi][1] = __builtin_amdgcn_mfma_f32_16x16x32_bf16(af[mi], bf2[1], acc[mi][1], 0, 0, 0);
        }
        __builtin_amdgcn_s_setprio(0);
        __builtin_amdgcn_s_barrier();

        bf2[0] = *(const bf16x8*)&BsF[k0 + bBase + 2 * 512];
        bf2[1] = *(const bf16x8*)&BsF[k0 + bBase + 3 * 512];
        if (t + 1 < nt) stageB(b ^ 1, 1, t + 1);
        __builtin_amdgcn_s_barrier(); lgkm0();
        __builtin_amdgcn_s_setprio(1);
#pragma unroll
        for (int mi = 0; mi < 8; mi++) {
            acc[mi][2] = __builtin_amdgcn_mfma_f32_16x16x32_bf16(af[mi], bf2[0], acc[mi][2], 0, 0, 0);
            acc[mi][3] = __builtin_amdgcn_mfma_f32_16x16x32_bf16(af[mi], bf2[1], acc[mi][3], 0, 0, 0);
        }
        __builtin_amdgcn_s_setprio(0);
        __builtin_amdgcn_s_barrier();

#pragma unroll
        for (int mi = 0; mi < 8; mi++) af[mi] = *(const bf16x8*)&AsF[k1 + aBase + mi * 512];
        bf2[0] = *(const bf16x8*)&BsF[k1 + bBase + 0 * 512];
        bf2[1] = *(const bf16x8*)&BsF[k1 + bBase + 1 * 512];
        if (t + 2 < nt) stageA(b, 0, t + 2);
        __builtin_amdgcn_s_barrier(); lgkm0();
        __builtin_amdgcn_s_setprio(1);
#pragma unroll
        for (int mi = 0; mi < 8; mi++) {
            acc[mi][0] = __builtin_amdgcn_mfma_f32_16x16x32_bf16(af[mi], bf2[0], acc[mi][0], 0, 0, 0);
            acc[mi][1] = __builtin_amdgcn_mfma_f32_16x16x32_bf16(af[mi], bf2[1], acc[mi][1], 0, 0, 0);
        }
        __builtin_amdgcn_s_setprio(0);
        __builtin_amdgcn_s_barrier();

        bf2[0] = *(const bf16x8*)&BsF[k1 + bBase + 2 * 512];
        bf2[1] = *(const bf16x8*)&BsF[k1 + bBase + 3 * 512];
        if (t + 2 < nt) stageB(b, 0, t + 2);
        __builtin_amdgcn_s_barrier(); lgkm0();
        __builtin_amdgcn_s_setprio(1);
#pragma unroll
        for (int mi = 0; mi < 8; mi++) {
            acc[mi][2] = __builtin_amdgcn_mfma_f32_16x16x32_bf16(af[mi], bf2[0], acc[mi][2], 0, 0, 0);
            acc[mi][3] = __builtin_amdgcn_mfma_f32_16x16x32_bf16(af[mi], bf2[1], acc[mi][3], 0, 0, 0);
        }
        __builtin_amdgcn_s_setprio(0);
        if (t + 2 < nt) wait_vm<4>();
        else            wait_vm<0>();
        __builtin_amdgcn_s_barrier();
        __builtin_amdgcn_sched_barrier(0);
    }

    // epilogue: LN fold + per-wave LDS transpose + coalesced 16B stores
    __hip_bfloat16* scr = AsF + wid * (16 * 72);
#pragma unroll
    for (int mi = 0; mi < 8; mi++) {
        float2 st[4];
#pragma unroll
        for (int r = 0; r < 4; r++)
            st[r] = stats[bm + wmh * 128 + mi * 16 + 4 * g + r];
#pragma unroll
        for (int ni = 0; ni < 4; ni++) {
            int gcol = bn + wnn * 64 + ni * 16 + l16;
            float c1 = c1v[gcol], c2 = c2v[gcol];
#pragma unroll
            for (int r = 0; r < 4; r++) {
                float v = st[r].y * (acc[mi][ni][r] - st[r].x * c2) + c1;
                if (GELU) v = 0.5f * v * (1.0f + erff(v * 0.70710678118654752f));
                scr[(4 * g + r) * 72 + ni * 16 + l16] = __float2bfloat16(v);
            }
        }
        lgkm0();
#pragma unroll
        for (int q2 = 0; q2 < 2; q2++) {
            int idx = q2 * 64 + lane;
            int row16 = idx >> 3, ch = idx & 7;
            bf16x8 vv = *(const bf16x8*)&scr[row16 * 72 + ch * 8];
            int grow = bm + wmh * 128 + mi * 16 + row16;
            *(int4*)&Cb[(size_t)grow * N + bn + wnn * 64 + ch * 8] = *(int4*)&vv;
        }
        lgkm0();
    }
}

// ---------------- narrow GEMM: BM=64 x BN=128, BK=64, 3-deep counted-vmcnt, bf16 out ----------
template <bool BIAS, bool RESID, bool GELU>
__global__ __launch_bounds__(256, 2) void gemm_bt_kernel(
    const __hip_bfloat16* __restrict__ A,
    const __hip_bfloat16* __restrict__ Bt,
    const float* __restrict__ bias,
    const __hip_bfloat16* __restrict__ resid,
    __hip_bfloat16* __restrict__ Cb,
    int M, int N, int K, int gx)
{
    constexpr int BM = 64;
    __shared__ __align__(16) __hip_bfloat16 As[3][BM * 64];
    __shared__ __align__(16) __hip_bfloat16 Bs[3][128 * 64];
    const int tid = threadIdx.x;
    const int wid = tid >> 6, lane = tid & 63;
    const int g = lane >> 4, l16 = lane & 15;
    const int wm = (wid >> 1) * 32, wn = (wid & 1) * 64;

    int2 bc = remap2d(blockIdx.x, gridDim.x, gx);
    const int bm = bc.x * BM, bn = bc.y * 128;

    const int sr32 = tid >> 3, ci = tid & 7;
    const int cg = ci ^ (sr32 & 7);
    const int sdst = tid * 8;
    size_t aOff[2], bOff[4];
#pragma unroll
    for (int i = 0; i < 2; i++) aOff[i] = (size_t)(bm + i * 32 + sr32) * K + cg * 8;
#pragma unroll
    for (int i = 0; i < 4; i++) bOff[i] = (size_t)(bn + i * 32 + sr32) * K + cg * 8;

    auto stage = [&](__hip_bfloat16* asb, __hip_bfloat16* bsb, int tq) {
        const __hip_bfloat16* ap = A + tq * 64;
        const __hip_bfloat16* bp = Bt + tq * 64;
#pragma unroll
        for (int i = 0; i < 2; i++) gload_lds16(ap + aOff[i], asb + i * 2048 + sdst);
#pragma unroll
        for (int i = 0; i < 4; i++) gload_lds16(bp + bOff[i], bsb + i * 2048 + sdst);
    };

    f32x4 acc[2][4] = {};
    const int nt = K >> 6;

    stage(As[0], Bs[0], 0);
    stage(As[1], Bs[1], 1);
    stage(As[2], Bs[2], 2);
    wait_vm<12>();
    __builtin_amdgcn_s_barrier();
    __builtin_amdgcn_sched_barrier(0);

    for (int t = 0; t < nt; t += 3) {
#pragma unroll
        for (int u = 0; u < 3; u++) {
            const int tc = t + u;
            bf16x8 af[2][2], bfr[2][4];
#pragma unroll
            for (int s = 0; s < 2; s++) {
                const int cp = ((s * 4 + g) ^ (l16 & 7)) << 3;
#pragma unroll
                for (int mi = 0; mi < 2; mi++)
                    af[s][mi] = *(const bf16x8*)&As[u][(wm + mi * 16 + l16) * 64 + cp];
#pragma unroll
                for (int ni = 0; ni < 4; ni++)
                    bfr[s][ni] = *(const bf16x8*)&Bs[u][(wn + ni * 16 + l16) * 64 + cp];
            }
#pragma unroll
            for (int s = 0; s < 2; s++)
#pragma unroll
                for (int mi = 0; mi < 2; mi++)
#pragma unroll
                    for (int ni = 0; ni < 4; ni++)
                        acc[mi][ni] = __builtin_amdgcn_mfma_f32_16x16x32_bf16(af[s][mi], bfr[s][ni], acc[mi][ni], 0, 0, 0);

            lgkm0();
            __builtin_amdgcn_s_barrier();
            __builtin_amdgcn_sched_barrier(0);

            if (tc + 3 < nt) stage(As[u], Bs[u], tc + 3);
            if (tc + 1 < nt) {
                if (tc + 4 <= nt)      wait_vm<12>();
                else if (tc + 3 == nt) wait_vm<6>();
                else                   wait_vm<0>();
                __builtin_amdgcn_s_barrier();
                __builtin_amdgcn_sched_barrier(0);
            }
        }
    }

    __hip_bfloat16* scr = &As[0][0] + wid * (16 * 72);
#pragma unroll
    for (int mi = 0; mi < 2; mi++) {
#pragma unroll
        for (int ni = 0; ni < 4; ni++) {
            float bval = 0.0f;
            if (BIAS) bval = bias[bn + wn + ni * 16 + l16];
#pragma unroll
            for (int r = 0; r < 4; r++) {
                float v = acc[mi][ni][r] + bval;
                if (GELU) v = 0.5f * v * (1.0f + erff(v * 0.70710678118654752f));
                scr[(4 * g + r) * 72 + ni * 16 + l16] = __float2bfloat16(v);
            }
        }
        lgkm0();
#pragma unroll
        for (int q2 = 0; q2 < 2; q2++) {
            int row16 = q2 * 8 + (lane >> 3), ch = lane & 7;
            bf16x8 vv = *(const bf16x8*)&scr[row16 * 72 + ch * 8];
            int grow = bm + wm + mi * 16 + row16;
            size_t off = (size_t)grow * N + bn + wn + ch * 8;
            if (RESID) {
                bf16x8 rv = *(const bf16x8*)&resid[off];
#pragma unroll
                for (int e = 0; e < 8; e++)
                    vv[e] = (short)f2bf_bits(bfbits2f((unsigned short)vv[e]) + bfbits2f((unsigned short)rv[e]));
            }
            *(int4*)&Cb[off] = *(int4*)&vv;
        }
        lgkm0();
    }
}

// ---------------- MFMA flash attention: softmax(q@k^T*scale + bias) @ v ----------------
__global__ __launch_bounds__(256) void attn_kernel(const __hip_bfloat16* __restrict__ qkvb,
                                                   const float* __restrict__ bias,   // [12][576][576] this layer
                                                   unsigned short* __restrict__ o)   // bf16 [4608][768]
{
    const int seq = (blockIdx.x & 7) * 108 + (blockIdx.x >> 3);
    const int bb = seq & 7, qt = (seq >> 3) % 9, h = seq / 72;
    const int q0 = qt * 64;
    const int tid = threadIdx.x;
    const int wq = tid >> 6, lane = tid & 63, g = lane >> 4, l16 = lane & 15;

    __shared__ __align__(16) unsigned short Qs[64 * 72];
    __shared__ __align__(16) unsigned short Ks[64 * 72];
    __shared__ __align__(16) unsigned short Vt[64 * 72];
    __shared__ __align__(16) unsigned short Ps[4][16 * 72];

    {
        int r = tid >> 2, cb = (tid & 3) * 16;
        const int4* s4 = (const int4*)&qkvb[(size_t)(bb * 576 + q0 + r) * 2304 + h * 64 + cb];
        int4* d4 = (int4*)&Qs[r * 72 + cb];
        d4[0] = s4[0]; d4[1] = s4[1];
    }
    __syncthreads();
    bf16x8 qf0 = *(const bf16x8*)&Qs[(wq * 16 + l16) * 72 + g * 8];
    bf16x8 qf1 = *(const bf16x8*)&Qs[(wq * 16 + l16) * 72 + 32 + g * 8];

    float m_r[4] = {-1e30f, -1e30f, -1e30f, -1e30f};
    float l_r[4] = {0.f, 0.f, 0.f, 0.f};
    f32x4 oa[4] = {};
    const float* bias_h = bias + (size_t)h * 576 * 576;
    const float scale = 0.125f;

    for (int kt = 0; kt < 576; kt += 64) {
        {
            int r = tid >> 2, cb = (tid & 3) * 16;
            const int4* s4 = (const int4*)&qkvb[(size_t)(bb * 576 + kt + r) * 2304 + 768 + h * 64 + cb];
            int4* d4 = (int4*)&Ks[r * 72 + cb];
            d4[0] = s4[0]; d4[1] = s4[1];
            int key = tid & 63, d0 = (tid >> 6) * 16;
            const unsigned short* vs = (const unsigned short*)&qkvb[(size_t)(bb * 576 + kt + key) * 2304 + 1536 + h * 64 + d0];
            bf16x8 v0 = *(const bf16x8*)vs;
            bf16x8 v1 = *(const bf16x8*)(vs + 8);
#pragma unroll
            for (int e = 0; e < 8; e++) {
                Vt[(d0 + e) * 72 + key] = (unsigned short)v0[e];
                Vt[(d0 + 8 + e) * 72 + key] = (unsigned short)v1[e];
            }
        }
        __syncthreads();

        float bl[4][4];
#pragma unroll
        for (int kc = 0; kc < 4; kc++)
#pragma unroll
            for (int r = 0; r < 4; r++) {
                int q = q0 + wq * 16 + 4 * g + r;
                bl[kc][r] = bias_h[(size_t)q * 576 + kt + kc * 16 + l16];
            }

        f32x4 sc[4] = {};
        __builtin_amdgcn_s_setprio(1);
#pragma unroll
        for (int kc = 0; kc < 4; kc++) {
            bf16x8 kf0 = *(const bf16x8*)&Ks[(kc * 16 + l16) * 72 + g * 8];
            bf16x8 kf1 = *(const bf16x8*)&Ks[(kc * 16 + l16) * 72 + 32 + g * 8];
            sc[kc] = __builtin_amdgcn_mfma_f32_16x16x32_bf16(qf0, kf0, sc[kc], 0, 0, 0);
            sc[kc] = __builtin_amdgcn_mfma_f32_16x16x32_bf16(qf1, kf1, sc[kc], 0, 0, 0);
        }
        __builtin_amdgcn_s_setprio(0);

        float sv[4][4], mt[4] = {-1e30f, -1e30f, -1e30f, -1e30f};
#pragma unroll
        for (int kc = 0; kc < 4; kc++)
#pragma unroll
            for (int r = 0; r < 4; r++) {
                float s = sc[kc][r] * scale + bl[kc][r];
                sv[kc][r] = s;
                mt[r] = fmaxf(mt[r], s);
            }
#pragma unroll
        for (int r = 0; r < 4; r++)
#pragma unroll
            for (int m = 1; m < 16; m <<= 1) mt[r] = fmaxf(mt[r], __shfl_xor(mt[r], m));

        float sf[4];
#pragma unroll
        for (int r = 0; r < 4; r++) {
            float mn = fmaxf(m_r[r], mt[r]);
            sf[r] = __expf(m_r[r] - mn);
            m_r[r] = mn;
        }
        float rs[4] = {0.f, 0.f, 0.f, 0.f};
#pragma unroll
        for (int kc = 0; kc < 4; kc++)
#pragma unroll
            for (int r = 0; r < 4; r++) {
                float p = __expf(sv[kc][r] - m_r[r]);
                rs[r] += p;
                Ps[wq][(4 * g + r) * 72 + kc * 16 + l16] = f2bf_bits(p);
            }
#pragma unroll
        for (int r = 0; r < 4; r++) {
#pragma unroll
            for (int m = 1; m < 16; m <<= 1) rs[r] += __shfl_xor(rs[r], m);
            l_r[r] = l_r[r] * sf[r] + rs[r];
        }
#pragma unroll
        for (int dt = 0; dt < 4; dt++)
#pragma unroll
            for (int r = 0; r < 4; r++) oa[dt][r] *= sf[r];

        asm volatile("s_waitcnt lgkmcnt(0)" ::: "memory");

        __builtin_amdgcn_s_setprio(1);
#pragma unroll
        for (int s = 0; s < 2; s++) {
            bf16x8 pf = *(const bf16x8*)&Ps[wq][l16 * 72 + s * 32 + g * 8];
#pragma unroll
            for (int dt = 0; dt < 4; dt++) {
                bf16x8 vf = *(const bf16x8*)&Vt[(dt * 16 + l16) * 72 + s * 32 + g * 8];
                oa[dt] = __builtin_amdgcn_mfma_f32_16x16x32_bf16(pf, vf, oa[dt], 0, 0, 0);
            }
        }
        __builtin_amdgcn_s_setprio(0);
        __syncthreads();
    }

#pragma unroll
    for (int dt = 0; dt < 4; dt++)
#pragma unroll
        for (int r = 0; r < 4; r++) {
            int q = q0 + wq * 16 + 4 * g + r;
            float v = oa[dt][r] / l_r[r];
            o[(size_t)(bb * 576 + q) * 768 + h * 64 + dt * 16 + l16] = f2bf_bits(v);
        }
}

// ---------------- mean pool over 576 tokens (bf16 in) ----------------
__global__ __launch_bounds__(256) void pool_kernel(const __hip_bfloat16* __restrict__ tok,
                                                   float* __restrict__ pooled)
{
    int d = blockIdx.x * 256 + threadIdx.x;
    int b = blockIdx.y;
    float s = 0.0f;
    for (int n = 0; n < 576; n++) s += __bfloat162float(tok[(size_t)(b * 576 + n) * 768 + d]);
    pooled[b * 768 + d] = s * (1.0f / 576.0f);
}

// ---------------- classifier head ----------------
__global__ __launch_bounds__(256) void head_kernel(const float* __restrict__ lnp,
                                                   const float* __restrict__ w,
                                                   const float* __restrict__ bh,
                                                   float* __restrict__ out)
{
    int c = blockIdx.x * 256 + threadIdx.x;
    int b = blockIdx.y;
    if (c >= 1000) return;
    float s = bh[c];
    for (int d = 0; d < 768; d++) s += lnp[b * 768 + d] * w[(size_t)d * 1000 + c];
    out[b * 1000 + c] = s;
}

extern "C" void kernel_launch(void* const* d_in, const int* in_sizes, int n_in,
                              void* d_out, int out_size, void* d_ws, size_t ws_size,
                              hipStream_t stream)
{
    const float* x = (const float*)d_in[0];
    const float* patch_w = (const float*)d_in[1];
    const float* patch_b = (const float*)d_in[2];
    const float* ln1_g = (const float*)d_in[3];
    const float* ln1_b = (const float*)d_in[4];
    const float* w_qkv = (const float*)d_in[5];
    const float* bias_att = (const float*)d_in[6];
    const float* w_out = (const float*)d_in[7];
    const float* ln2_g = (const float*)d_in[8];
    const float* ln2_b = (const float*)d_in[9];
    const float* w1 = (const float*)d_in[10];
    const float* b1 = (const float*)d_in[11];
    const float* w2 = (const float*)d_in[12];
    const float* b2 = (const float*)d_in[13];
    const float* lnh_g = (const float*)d_in[14];
    const float* lnh_b = (const float*)d_in[15];
    const float* w_head = (const float*)d_in[16];
    const float* b_head = (const float*)d_in[17];
    float* out = (float*)d_out;

    char* ws = (char*)d_ws;
    __hip_bfloat16* tok = (__hip_bfloat16*)(ws + 0);             // 4608*768 bf16
    __hip_bfloat16* qkv_bf = (__hip_bfloat16*)(ws + 14155776);   // 4608*2304 bf16
    float* coef = (float*)(ws + 35389440);                       // 4*10752 f32 = 172,032 B
    float2* stats = (float2*)(ws + 35561856);                    // 4608 float2 = 36,864 B
    float* pooled = (float*)(ws + 56623104);
    float* pooledln = (float*)(ws + 56647680);
    __hip_bfloat16* patches = (__hip_bfloat16*)(ws + 56672256);  // 4608*1536 bf16
    __hip_bfloat16* lw = patches;                                // per-layer weights (fallback path)
    __hip_bfloat16* o_bf = (__hip_bfloat16*)(ws + 77905920);
    __hip_bfloat16* hid_bf = (__hip_bfloat16*)(ws + 84983808);
    __hip_bfloat16* wbuf = (__hip_bfloat16*)(ws + 113295360);    // patch weight 768*1536 bf16
    __hip_bfloat16* lwAll = (__hip_bfloat16*)(ws + 118013952);   // all-layers weights (gated)
    const bool useAll = ws_size >= (size_t)118013952 + 56623104;

    // patch embedding + one-shot weight prep
    patchify_kernel<<<3456, 256, 0, stream>>>(x, (unsigned short*)patches);
    convT_patch_kernel<<<dim3(24, 48), 256, 0, stream>>>(patch_w, wbuf);
    lncoef_kernel<<<dim3(21, 4), 256, 0, stream>>>(w_qkv, w1, ln1_g, ln1_b, ln2_g, ln2_b, b1, coef);
    gemm_bt_kernel<true, false, false><<<432, 256, 0, stream>>>(
        patches, wbuf, patch_b, nullptr, tok, 4608, 768, 1536, 6);

    if (useAll)
        convT4all_kernel<<<27648, 256, 0, stream>>>(w_qkv, w_out, w1, w2, ln1_g, ln2_g, lwAll);

    for (int l = 0; l < 4; l++) {
        __hip_bfloat16* lwl = useAll ? lwAll + (size_t)l * 7077888 : lw;
        const float* cf = coef + (size_t)l * 10752;
        if (!useAll)
            convT4_kernel<<<6912, 256, 0, stream>>>(
                w_qkv + (size_t)l * 768 * 2304, w_out + (size_t)l * 768 * 768,
                w1 + (size_t)l * 768 * 3072, w2 + (size_t)l * 3072 * 768,
                ln1_g + l * 768, ln2_g + l * 768, lw);
        // attn sub-block (LN1 folded into qkv GEMM)
        stats_kernel<<<1152, 256, 0, stream>>>(tok, stats);
        gemm_8ph_kernel<false><<<162, 512, 0, stream>>>(
            tok, lwl, stats, cf, cf + 2304, qkv_bf, 4608, 2304, 768, 9);
        attn_kernel<<<864, 256, 0, stream>>>(
            qkv_bf, bias_att + (size_t)l * 12 * 576 * 576, (unsigned short*)o_bf);
        gemm_bt_kernel<false, true, false><<<432, 256, 0, stream>>>(
            o_bf, lwl + 1769472, nullptr, tok, tok, 4608, 768, 768, 6);
        // mlp sub-block (LN2 + b1 folded into up GEMM)
        stats_kernel<<<1152, 256, 0, stream>>>(tok, stats);
        gemm_8ph_kernel<true><<<216, 512, 0, stream>>>(
            tok, lwl + 2359296, stats, cf + 4608, cf + 4608 + 3072, hid_bf, 4608, 3072, 768, 12);
        gemm_bt_kernel<true, true, false><<<432, 256, 0, stream>>>(
            hid_bf, lwl + 4718592, b2 + l * 768, tok, tok, 4608, 768, 3072, 6);
    }

    pool_kernel<<<dim3(3, 8), 256, 0, stream>>>(tok, pooled);
    lnf_kernel<<<8, 192, 0, stream>>>(pooled, lnh_g, lnh_b, pooledln);
    head_kernel<<<dim3(4, 8), 256, 0, stream>>>(pooledln, w_head, b_head, out);
}

// Round 12
// 840.424 us; speedup vs baseline: 1.0776x; 1.0714x over previous
//
#include <hip/hip_runtime.h>
#include <hip/hip_bf16.h>

typedef __attribute__((ext_vector_type(8))) short bf16x8;
typedef __attribute__((ext_vector_type(4))) float f32x4;

#define DEVI __device__ __forceinline__

DEVI unsigned short f2bf_bits(float f) {
    __hip_bfloat16 h = __float2bfloat16(f);
    return *reinterpret_cast<unsigned short*>(&h);
}
DEVI float bfbits2f(unsigned short u) {
    __hip_bfloat16 h = *reinterpret_cast<__hip_bfloat16*>(&u);
    return __bfloat162float(h);
}

// async global->LDS, 16B per lane. LDS dest is wave-uniform base + lane*16 (linear).
DEVI void gload_lds16(const void* g, void* lds) {
    __builtin_amdgcn_global_load_lds(
        (const __attribute__((address_space(1))) unsigned int*)g,
        (__attribute__((address_space(3))) unsigned int*)lds, 16, 0, 0);
}

template <int N> DEVI void wait_vm() {
    if constexpr (N == 0) asm volatile("s_waitcnt vmcnt(0)" ::: "memory");
    else if constexpr (N == 4) asm volatile("s_waitcnt vmcnt(4)" ::: "memory");
    else if constexpr (N == 6) asm volatile("s_waitcnt vmcnt(6)" ::: "memory");
    else if constexpr (N == 12) asm volatile("s_waitcnt vmcnt(12)" ::: "memory");
    __builtin_amdgcn_sched_barrier(0);
}
DEVI void lgkm0() {
    asm volatile("s_waitcnt lgkmcnt(0)" ::: "memory");
    __builtin_amdgcn_sched_barrier(0);
}

// bijective XCD chunking (m204) + group-of-4-rows locality (requires nrow%4==0)
DEVI int2 remap2d(int bid, int total, int gx) {
    int q = total >> 3, r = total & 7, x = bid & 7, l = bid >> 3;
    int seq = (x < r ? x * (q + 1) : r * (q + 1) + (x - r) * q) + l;
    int g4 = seq / (4 * gx);
    int rem = seq - g4 * 4 * gx;
    return {g4 * 4 + (rem & 3), rem >> 2};   // (by, bx)
}
// group-of-2 variant — used by 256-tile kernels
DEVI int2 remap2d_g2(int bid, int total, int gx) {
    int q = total >> 3, r = total & 7, x = bid & 7, l = bid >> 3;
    int seq = (x < r ? x * (q + 1) : r * (q + 1) + (x - r) * q) + l;
    int g2 = seq / (2 * gx);
    int rem = seq - g2 * 2 * gx;
    return {g2 * 2 + (rem & 1), rem >> 1};
}

// ---------------- patchify: x[B,C,384,384] -> patches bf16 [4608][1536] (c-major patch dim) ----
__global__ __launch_bounds__(256) void patchify_kernel(const float* __restrict__ x,
                                                       unsigned short* __restrict__ patches)
{
    size_t t8 = (size_t)blockIdx.x * 256 + threadIdx.x;   // 884,736 threads, 8 floats each
    int jq = (int)(t8 % 48);
    size_t t = t8 / 48;
    int r = (int)(t % 384); t /= 384;
    int c = (int)(t % 6);
    int b = (int)(t / 6);
    int j = jq * 8;
    int gh = r >> 4, p1 = r & 15, gw = j >> 4, p2 = j & 15;
    int prow = b * 576 + gh * 24 + gw;
    int pcol = c * 256 + p1 * 16 + p2;
    const float* src = x + ((((size_t)b * 6 + c) * 384 + r) * 384 + j);
    float4 v0 = ((const float4*)src)[0];
    float4 v1 = ((const float4*)src)[1];
    ushort u[8] = { f2bf_bits(v0.x), f2bf_bits(v0.y), f2bf_bits(v0.z), f2bf_bits(v0.w),
                    f2bf_bits(v1.x), f2bf_bits(v1.y), f2bf_bits(v1.z), f2bf_bits(v1.w) };
    *(int4*)&patches[(size_t)prow * 1536 + pcol] = *(int4*)u;
}

// ---------------- patch-weight convert: W f32 [1536][768] -> Wt bf16 [768][1536'] (k-permuted) --
__global__ __launch_bounds__(256) void convT_patch_kernel(const float* __restrict__ W,
                                                          __hip_bfloat16* __restrict__ Wt)
{
    __shared__ float tile[32][33];
    int n0 = blockIdx.x * 32, kp0 = blockIdx.y * 32;
    int tx = threadIdx.x & 31, ty = threadIdx.x >> 5;
#pragma unroll
    for (int i = 0; i < 4; i++) {
        int kp = kp0 + ty + 8 * i;
        int k = (kp & 255) * 6 + (kp >> 8);   // inverse of k' = c*256 + pp
        tile[ty + 8 * i][tx] = W[(size_t)k * 768 + n0 + tx];
    }
    __syncthreads();
#pragma unroll
    for (int i = 0; i < 4; i++)
        Wt[(size_t)(n0 + ty + 8 * i) * 1536 + kp0 + tx] = __float2bfloat16(tile[tx][ty + 8 * i]);
}

// ---------------- weight convert + transpose + LN-fold partials ----------------
// For qkv/w1 blocks: fold g into Wt AND emit per-k-tile partial sums of c1 = sum b*W,
// c2 = sum g*W (computed from the already-staged LDS tile — zero extra global reads).
// part layout (per layer): [24 ktiles][2 (c1,c2)][5376 n]  (n: 0..2303 qkv, 2304..5375 w1)
DEVI void convT4_dispatch(int bt, const float* wqkv, const float* wout,
                          const float* w1, const float* w2,
                          const float* g1, const float* b1ln,
                          const float* g2, const float* b2ln,
                          __hip_bfloat16* dst, float* part, int tid)
{
    const float* W; const float* gv = nullptr; const float* bv = nullptr;
    __hip_bfloat16* Wt; int K, N, lt, nseg = 0;
    if (bt < 1728)      { W = wqkv; K = 768;  N = 2304; lt = bt;        Wt = dst;           gv = g1; bv = b1ln; nseg = 0; }
    else if (bt < 2304) { W = wout; K = 768;  N = 768;  lt = bt - 1728; Wt = dst + 1769472; }
    else if (bt < 4608) { W = w1;   K = 768;  N = 3072; lt = bt - 2304; Wt = dst + 2359296; gv = g2; bv = b2ln; nseg = 2304; }
    else                { W = w2;   K = 3072; N = 768;  lt = bt - 4608; Wt = dst + 4718592; }
    int tn = N >> 5;
    int k0 = (lt / tn) * 32, n0 = (lt % tn) * 32;

    __shared__ float tile[32][33];
    int tx = tid & 31, ty = tid >> 5;
#pragma unroll
    for (int i = 0; i < 4; i++)
        tile[ty + 8 * i][tx] = W[(size_t)(k0 + ty + 8 * i) * N + n0 + tx];
    __syncthreads();
    float gk = gv ? gv[k0 + tx] : 1.0f;
#pragma unroll
    for (int i = 0; i < 4; i++)
        Wt[(size_t)(n0 + ty + 8 * i) * K + k0 + tx] = __float2bfloat16(tile[tx][ty + 8 * i] * gk);
    if (gv && tid < 64) {
        int nn = tid & 31, j = tid >> 5;          // j=0: c1 (ln bias), j=1: c2 (ln gain)
        const float* vec = j ? gv : bv;
        float s = 0.f;
#pragma unroll
        for (int kk = 0; kk < 32; kk++) s += vec[k0 + kk] * tile[kk][nn];
        int kt = k0 >> 5;
        part[((size_t)kt * 2 + j) * 5376 + nseg + n0 + nn] = s;
    }
}

__global__ __launch_bounds__(256) void convT4_kernel(const float* __restrict__ wqkv,
                                                     const float* __restrict__ wout,
                                                     const float* __restrict__ w1,
                                                     const float* __restrict__ w2,
                                                     const float* __restrict__ g1,
                                                     const float* __restrict__ b1ln,
                                                     const float* __restrict__ g2,
                                                     const float* __restrict__ b2ln,
                                                     __hip_bfloat16* __restrict__ dst,
                                                     float* __restrict__ part)
{
    convT4_dispatch(blockIdx.x, wqkv, wout, w1, w2, g1, b1ln, g2, b2ln, dst, part, threadIdx.x);
}

__global__ __launch_bounds__(256) void convT4all_kernel(const float* __restrict__ wqkv,
                                                        const float* __restrict__ wout,
                                                        const float* __restrict__ w1,
                                                        const float* __restrict__ w2,
                                                        const float* __restrict__ ln1_g,
                                                        const float* __restrict__ ln1_b,
                                                        const float* __restrict__ ln2_g,
                                                        const float* __restrict__ ln2_b,
                                                        __hip_bfloat16* __restrict__ dst,
                                                        float* __restrict__ part)
{
    int l = blockIdx.x / 6912, bt = blockIdx.x % 6912;
    convT4_dispatch(bt,
                    wqkv + (size_t)l * 768 * 2304, wout + (size_t)l * 768 * 768,
                    w1 + (size_t)l * 768 * 3072, w2 + (size_t)l * 3072 * 768,
                    ln1_g + l * 768, ln1_b + l * 768, ln2_g + l * 768, ln2_b + l * 768,
                    dst + (size_t)l * 7077888, part + (size_t)l * 258048, threadIdx.x);
}

// ---------------- reduce partials -> coef: [c1q 2304][c2q 2304][c1u 3072][c2u 3072] per layer --
__global__ __launch_bounds__(256) void lnreduce_kernel(const float* __restrict__ part,
                                                       const float* __restrict__ b1,
                                                       float* __restrict__ coef,
                                                       int lbase)
{
    int l = lbase + blockIdx.y;
    const float* p = part + (size_t)blockIdx.y * 258048;   // 24*2*5376
    int n = blockIdx.x * 256 + threadIdx.x;                // 0..5375
    float s1 = 0.f, s2 = 0.f;
    for (int kt = 0; kt < 24; kt++) {
        s1 += p[((size_t)kt * 2 + 0) * 5376 + n];
        s2 += p[((size_t)kt * 2 + 1) * 5376 + n];
    }
    float* dst = coef + (size_t)l * 10752;
    if (n < 2304) { dst[n] = s1; dst[2304 + n] = s2; }
    else {
        int n0 = n - 2304;
        dst[4608 + n0] = s1 + b1[(size_t)l * 3072 + n0];
        dst[4608 + 3072 + n0] = s2;
    }
}

// ---------------- per-row mean/rstd of tok: stats[row] = (mu, rstd) ----------------
__global__ __launch_bounds__(256) void stats_kernel(const __hip_bfloat16* __restrict__ tok,
                                                    float2* __restrict__ stats)
{
    int row = blockIdx.x * 4 + (threadIdx.x >> 6);
    int lane = threadIdx.x & 63;
    const unsigned short* tr = (const unsigned short*)(tok + (size_t)row * 768) + lane * 12;
    float s = 0.f, s2 = 0.f;
#pragma unroll
    for (int i = 0; i < 3; i++) {
        ushort4 u = ((const ushort4*)tr)[i];
        float v0 = bfbits2f(u.x), v1 = bfbits2f(u.y), v2 = bfbits2f(u.z), v3 = bfbits2f(u.w);
        s += v0 + v1 + v2 + v3;
        s2 += v0 * v0 + v1 * v1 + v2 * v2 + v3 * v3;
    }
#pragma unroll
    for (int m = 32; m >= 1; m >>= 1) { s += __shfl_xor(s, m); s2 += __shfl_xor(s2, m); }
    if (lane == 0) {
        float mean = s * (1.0f / 768.0f);
        float var = s2 * (1.0f / 768.0f) - mean * mean;
        stats[row] = make_float2(mean, rsqrtf(var + 1e-5f));
    }
}

// ---------------- layernorm (float head path only) ----------------
__global__ __launch_bounds__(192) void lnf_kernel(const float* __restrict__ x,
                                                  const float* __restrict__ g,
                                                  const float* __restrict__ b,
                                                  float* __restrict__ out)
{
    int row = blockIdx.x, tid = threadIdx.x;
    float4 v4 = *(const float4*)&x[(size_t)row * 768 + tid * 4];
    float v[4] = {v4.x, v4.y, v4.z, v4.w};
    float s = v[0] + v[1] + v[2] + v[3];
    float s2 = v[0] * v[0] + v[1] * v[1] + v[2] * v[2] + v[3] * v[3];
#pragma unroll
    for (int m = 32; m >= 1; m >>= 1) { s += __shfl_xor(s, m); s2 += __shfl_xor(s2, m); }
    __shared__ float red[6];
    int w = tid >> 6;
    if ((tid & 63) == 0) { red[w] = s; red[3 + w] = s2; }
    __syncthreads();
    s = red[0] + red[1] + red[2];
    s2 = red[3] + red[4] + red[5];
    float mean = s * (1.0f / 768.0f);
    float var = s2 * (1.0f / 768.0f) - mean * mean;
    float rstd = rsqrtf(var + 1e-5f);
    float4 g4 = *(const float4*)&g[tid * 4];
    float4 b4 = *(const float4*)&b[tid * 4];
    float o[4] = { (v[0] - mean) * rstd * g4.x + b4.x, (v[1] - mean) * rstd * g4.y + b4.y,
                   (v[2] - mean) * rstd * g4.z + b4.z, (v[3] - mean) * rstd * g4.w + b4.w };
    *(float4*)&out[(size_t)row * 768 + tid * 4] = make_float4(o[0], o[1], o[2], o[3]);
}

// ================= 256x256 8-phase GEMM with LN fold: C = LNrow(A) @ (g W)^T via =================
//   C[r][n] = rstd_r * (acc[r][n] - mu_r * c2[n]) + c1[n]   (+gelu)
template <bool GELU>
__global__ __launch_bounds__(512, 2) void gemm_8ph_kernel(
    const __hip_bfloat16* __restrict__ A,
    const __hip_bfloat16* __restrict__ Bt,
    const float2* __restrict__ stats,
    const float* __restrict__ c1v,
    const float* __restrict__ c2v,
    __hip_bfloat16* __restrict__ Cb,
    int M, int N, int K, int gx)
{
    __shared__ __align__(16) __hip_bfloat16 AsF[32768];   // [2][2][256][32]
    __shared__ __align__(16) __hip_bfloat16 BsF[32768];
    const int tid = threadIdx.x;
    const int wid = tid >> 6, lane = tid & 63;
    const int g = lane >> 4, l16 = lane & 15;
    const int wmh = wid >> 2, wnn = wid & 3;

    int2 bc = remap2d_g2(blockIdx.x, gridDim.x, gx);
    const int bm = bc.x * 256, bn = bc.y * 256;

    const int srow = tid >> 2;
    size_t aS[2], bS[2];
#pragma unroll
    for (int i = 0; i < 2; i++) {
        int row = i * 128 + srow;
        int lc = (tid & 3) ^ ((row >> 1) & 3);
        aS[i] = (size_t)(bm + row) * K + lc * 8;
        bS[i] = (size_t)(bn + row) * K + lc * 8;
    }
    auto stageA = [&](int buf, int kh, int tq) {
        const __hip_bfloat16* ap = A + (size_t)tq * 64 + kh * 32;
        __hip_bfloat16* dst = AsF + (buf * 2 + kh) * 8192;
        gload_lds16(ap + aS[0], dst + tid * 8);
        gload_lds16(ap + aS[1], dst + 4096 + tid * 8);
    };
    auto stageB = [&](int buf, int kh, int tq) {
        const __hip_bfloat16* bp = Bt + (size_t)tq * 64 + kh * 32;
        __hip_bfloat16* dst = BsF + (buf * 2 + kh) * 8192;
        gload_lds16(bp + bS[0], dst + tid * 8);
        gload_lds16(bp + bS[1], dst + 4096 + tid * 8);
    };

    const int csw = (l16 >> 1) & 3;
    const int rdo = (g ^ csw) << 3;
    const int aBase = (wmh * 128 + l16) * 32 + rdo;
    const int bBase = (wnn * 64 + l16) * 32 + rdo;

    f32x4 acc[8][4] = {};
    const int nt = K >> 6;

    stageA(0, 0, 0); stageB(0, 0, 0); stageA(0, 1, 0); stageB(0, 1, 0);
    stageA(1, 0, 1); stageB(1, 0, 1);
    wait_vm<4>();
    __builtin_amdgcn_s_barrier();
    __builtin_amdgcn_sched_barrier(0);

    bf16x8 af[8], bf2[2];
    for (int t = 0; t < nt; t++) {
        const int b = t & 1;
        const int k0 = (b * 2 + 0) * 8192, k1 = (b * 2 + 1) * 8192;

#pragma unroll
        for (int mi = 0; mi < 8; mi++) af[mi] = *(const bf16x8*)&AsF[k0 + aBase + mi * 512];
        bf2[0] = *(const bf16x8*)&BsF[k0 + bBase + 0 * 512];
        bf2[1] = *(const bf16x8*)&BsF[k0 + bBase + 1 * 512];
        if (t + 1 < nt) stageA(b ^ 1, 1, t + 1);
        __builtin_amdgcn_s_barrier(); lgkm0();
        __builtin_amdgcn_s_setprio(1);
#pragma unroll
        for (int mi = 0; mi < 8; mi++) {
            acc[mi][0] = __builtin_amdgcn_mfma_f32_16x16x32_bf16(af[mi], bf2[0], acc[mi][0], 0, 0, 0);
            acc[mi][1] = __builtin_amdgcn_mfma_f32_16x16x32_bf16(af[mi], bf2[1], acc[mi][1], 0, 0, 0);
        }
        __builtin_amdgcn_s_setprio(0);
        __builtin_amdgcn_s_barrier();

        bf2[0] = *(const bf16x8*)&BsF[k0 + bBase + 2 * 512];
        bf2[1] = *(const bf16x8*)&BsF[k0 + bBase + 3 * 512];
        if (t + 1 < nt) stageB(b ^ 1, 1, t + 1);
        __builtin_amdgcn_s_barrier(); lgkm0();
        __builtin_amdgcn_s_setprio(1);
#pragma unroll
        for (int mi = 0; mi < 8; mi++) {
            acc[mi][2] = __builtin_amdgcn_mfma_f32_16x16x32_bf16(af[mi], bf2[0], acc[mi][2], 0, 0, 0);
            acc[mi][3] = __builtin_amdgcn_mfma_f32_16x16x32_bf16(af[mi], bf2[1], acc[mi][3], 0, 0, 0);
        }
        __builtin_amdgcn_s_setprio(0);
        __builtin_amdgcn_s_barrier();

#pragma unroll
        for (int mi = 0; mi < 8; mi++) af[mi] = *(const bf16x8*)&AsF[k1 + aBase + mi * 512];
        bf2[0] = *(const bf16x8*)&BsF[k1 + bBase + 0 * 512];
        bf2[1] = *(const bf16x8*)&BsF[k1 + bBase + 1 * 512];
        if (t + 2 < nt) stageA(b, 0, t + 2);
        __builtin_amdgcn_s_barrier(); lgkm0();
        __builtin_amdgcn_s_setprio(1);
#pragma unroll
        for (int mi = 0; mi < 8; mi++) {
            acc[mi][0] = __builtin_amdgcn_mfma_f32_16x16x32_bf16(af[mi], bf2[0], acc[mi][0], 0, 0, 0);
            acc[mi][1] = __builtin_amdgcn_mfma_f32_16x16x32_bf16(af[mi], bf2[1], acc[mi][1], 0, 0, 0);
        }
        __builtin_amdgcn_s_setprio(0);
        __builtin_amdgcn_s_barrier();

        bf2[0] = *(const bf16x8*)&BsF[k1 + bBase + 2 * 512];
        bf2[1] = *(const bf16x8*)&BsF[k1 + bBase + 3 * 512];
        if (t + 2 < nt) stageB(b, 0, t + 2);
        __builtin_amdgcn_s_barrier(); lgkm0();
        __builtin_amdgcn_s_setprio(1);
#pragma unroll
        for (int mi = 0; mi < 8; mi++) {
            acc[mi][2] = __builtin_amdgcn_mfma_f32_16x16x32_bf16(af[mi], bf2[0], acc[mi][2], 0, 0, 0);
            acc[mi][3] = __builtin_amdgcn_mfma_f32_16x16x32_bf16(af[mi], bf2[1], acc[mi][3], 0, 0, 0);
        }
        __builtin_amdgcn_s_setprio(0);
        if (t + 2 < nt) wait_vm<4>();
        else            wait_vm<0>();
        __builtin_amdgcn_s_barrier();
        __builtin_amdgcn_sched_barrier(0);
    }

    // epilogue: LN fold + per-wave LDS transpose + coalesced 16B stores
    __hip_bfloat16* scr = AsF + wid * (16 * 72);
#pragma unroll
    for (int mi = 0; mi < 8; mi++) {
        float2 st[4];
#pragma unroll
        for (int r = 0; r < 4; r++)
            st[r] = stats[bm + wmh * 128 + mi * 16 + 4 * g + r];
#pragma unroll
        for (int ni = 0; ni < 4; ni++) {
            int gcol = bn + wnn * 64 + ni * 16 + l16;
            float c1 = c1v[gcol], c2 = c2v[gcol];
#pragma unroll
            for (int r = 0; r < 4; r++) {
                float v = st[r].y * (acc[mi][ni][r] - st[r].x * c2) + c1;
                if (GELU) v = 0.5f * v * (1.0f + erff(v * 0.70710678118654752f));
                scr[(4 * g + r) * 72 + ni * 16 + l16] = __float2bfloat16(v);
            }
        }
        lgkm0();
#pragma unroll
        for (int q2 = 0; q2 < 2; q2++) {
            int idx = q2 * 64 + lane;
            int row16 = idx >> 3, ch = idx & 7;
            bf16x8 vv = *(const bf16x8*)&scr[row16 * 72 + ch * 8];
            int grow = bm + wmh * 128 + mi * 16 + row16;
            *(int4*)&Cb[(size_t)grow * N + bn + wnn * 64 + ch * 8] = *(int4*)&vv;
        }
        lgkm0();
    }
}

// ---------------- narrow GEMM: BM=64 x BN=128, BK=64, 3-deep counted-vmcnt, bf16 out ----------
template <bool BIAS, bool RESID, bool GELU>
__global__ __launch_bounds__(256, 2) void gemm_bt_kernel(
    const __hip_bfloat16* __restrict__ A,
    const __hip_bfloat16* __restrict__ Bt,
    const float* __restrict__ bias,
    const __hip_bfloat16* __restrict__ resid,
    __hip_bfloat16* __restrict__ Cb,
    int M, int N, int K, int gx)
{
    constexpr int BM = 64;
    __shared__ __align__(16) __hip_bfloat16 As[3][BM * 64];
    __shared__ __align__(16) __hip_bfloat16 Bs[3][128 * 64];
    const int tid = threadIdx.x;
    const int wid = tid >> 6, lane = tid & 63;
    const int g = lane >> 4, l16 = lane & 15;
    const int wm = (wid >> 1) * 32, wn = (wid & 1) * 64;

    int2 bc = remap2d(blockIdx.x, gridDim.x, gx);
    const int bm = bc.x * BM, bn = bc.y * 128;

    const int sr32 = tid >> 3, ci = tid & 7;
    const int cg = ci ^ (sr32 & 7);
    const int sdst = tid * 8;
    size_t aOff[2], bOff[4];
#pragma unroll
    for (int i = 0; i < 2; i++) aOff[i] = (size_t)(bm + i * 32 + sr32) * K + cg * 8;
#pragma unroll
    for (int i = 0; i < 4; i++) bOff[i] = (size_t)(bn + i * 32 + sr32) * K + cg * 8;

    auto stage = [&](__hip_bfloat16* asb, __hip_bfloat16* bsb, int tq) {
        const __hip_bfloat16* ap = A + tq * 64;
        const __hip_bfloat16* bp = Bt + tq * 64;
#pragma unroll
        for (int i = 0; i < 2; i++) gload_lds16(ap + aOff[i], asb + i * 2048 + sdst);
#pragma unroll
        for (int i = 0; i < 4; i++) gload_lds16(bp + bOff[i], bsb + i * 2048 + sdst);
    };

    f32x4 acc[2][4] = {};
    const int nt = K >> 6;

    stage(As[0], Bs[0], 0);
    stage(As[1], Bs[1], 1);
    stage(As[2], Bs[2], 2);
    wait_vm<12>();
    __builtin_amdgcn_s_barrier();
    __builtin_amdgcn_sched_barrier(0);

    for (int t = 0; t < nt; t += 3) {
#pragma unroll
        for (int u = 0; u < 3; u++) {
            const int tc = t + u;
            bf16x8 af[2][2], bfr[2][4];
#pragma unroll
            for (int s = 0; s < 2; s++) {
                const int cp = ((s * 4 + g) ^ (l16 & 7)) << 3;
#pragma unroll
                for (int mi = 0; mi < 2; mi++)
                    af[s][mi] = *(const bf16x8*)&As[u][(wm + mi * 16 + l16) * 64 + cp];
#pragma unroll
                for (int ni = 0; ni < 4; ni++)
                    bfr[s][ni] = *(const bf16x8*)&Bs[u][(wn + ni * 16 + l16) * 64 + cp];
            }
#pragma unroll
            for (int s = 0; s < 2; s++)
#pragma unroll
                for (int mi = 0; mi < 2; mi++)
#pragma unroll
                    for (int ni = 0; ni < 4; ni++)
                        acc[mi][ni] = __builtin_amdgcn_mfma_f32_16x16x32_bf16(af[s][mi], bfr[s][ni], acc[mi][ni], 0, 0, 0);

            lgkm0();
            __builtin_amdgcn_s_barrier();
            __builtin_amdgcn_sched_barrier(0);

            if (tc + 3 < nt) stage(As[u], Bs[u], tc + 3);
            if (tc + 1 < nt) {
                if (tc + 4 <= nt)      wait_vm<12>();
                else if (tc + 3 == nt) wait_vm<6>();
                else                   wait_vm<0>();
                __builtin_amdgcn_s_barrier();
                __builtin_amdgcn_sched_barrier(0);
            }
        }
    }

    __hip_bfloat16* scr = &As[0][0] + wid * (16 * 72);
#pragma unroll
    for (int mi = 0; mi < 2; mi++) {
#pragma unroll
        for (int ni = 0; ni < 4; ni++) {
            float bval = 0.0f;
            if (BIAS) bval = bias[bn + wn + ni * 16 + l16];
#pragma unroll
            for (int r = 0; r < 4; r++) {
                float v = acc[mi][ni][r] + bval;
                if (GELU) v = 0.5f * v * (1.0f + erff(v * 0.70710678118654752f));
                scr[(4 * g + r) * 72 + ni * 16 + l16] = __float2bfloat16(v);
            }
        }
        lgkm0();
#pragma unroll
        for (int q2 = 0; q2 < 2; q2++) {
            int row16 = q2 * 8 + (lane >> 3), ch = lane & 7;
            bf16x8 vv = *(const bf16x8*)&scr[row16 * 72 + ch * 8];
            int grow = bm + wm + mi * 16 + row16;
            size_t off = (size_t)grow * N + bn + wn + ch * 8;
            if (RESID) {
                bf16x8 rv = *(const bf16x8*)&resid[off];
#pragma unroll
                for (int e = 0; e < 8; e++)
                    vv[e] = (short)f2bf_bits(bfbits2f((unsigned short)vv[e]) + bfbits2f((unsigned short)rv[e]));
            }
            *(int4*)&Cb[off] = *(int4*)&vv;
        }
        lgkm0();
    }
}

// ---------------- MFMA flash attention: softmax(q@k^T*scale + bias) @ v ----------------
__global__ __launch_bounds__(256) void attn_kernel(const __hip_bfloat16* __restrict__ qkvb,
                                                   const float* __restrict__ bias,   // [12][576][576] this layer
                                                   unsigned short* __restrict__ o)   // bf16 [4608][768]
{
    const int seq = (blockIdx.x & 7) * 108 + (blockIdx.x >> 3);
    const int bb = seq & 7, qt = (seq >> 3) % 9, h = seq / 72;
    const int q0 = qt * 64;
    const int tid = threadIdx.x;
    const int wq = tid >> 6, lane = tid & 63, g = lane >> 4, l16 = lane & 15;

    __shared__ __align__(16) unsigned short Qs[64 * 72];
    __shared__ __align__(16) unsigned short Ks[64 * 72];
    __shared__ __align__(16) unsigned short Vt[64 * 72];
    __shared__ __align__(16) unsigned short Ps[4][16 * 72];

    {
        int r = tid >> 2, cb = (tid & 3) * 16;
        const int4* s4 = (const int4*)&qkvb[(size_t)(bb * 576 + q0 + r) * 2304 + h * 64 + cb];
        int4* d4 = (int4*)&Qs[r * 72 + cb];
        d4[0] = s4[0]; d4[1] = s4[1];
    }
    __syncthreads();
    bf16x8 qf0 = *(const bf16x8*)&Qs[(wq * 16 + l16) * 72 + g * 8];
    bf16x8 qf1 = *(const bf16x8*)&Qs[(wq * 16 + l16) * 72 + 32 + g * 8];

    float m_r[4] = {-1e30f, -1e30f, -1e30f, -1e30f};
    float l_r[4] = {0.f, 0.f, 0.f, 0.f};
    f32x4 oa[4] = {};
    const float* bias_h = bias + (size_t)h * 576 * 576;
    const float scale = 0.125f;

    for (int kt = 0; kt < 576; kt += 64) {
        {
            int r = tid >> 2, cb = (tid & 3) * 16;
            const int4* s4 = (const int4*)&qkvb[(size_t)(bb * 576 + kt + r) * 2304 + 768 + h * 64 + cb];
            int4* d4 = (int4*)&Ks[r * 72 + cb];
            d4[0] = s4[0]; d4[1] = s4[1];
            int key = tid & 63, d0 = (tid >> 6) * 16;
            const unsigned short* vs = (const unsigned short*)&qkvb[(size_t)(bb * 576 + kt + key) * 2304 + 1536 + h * 64 + d0];
            bf16x8 v0 = *(const bf16x8*)vs;
            bf16x8 v1 = *(const bf16x8*)(vs + 8);
#pragma unroll
            for (int e = 0; e < 8; e++) {
                Vt[(d0 + e) * 72 + key] = (unsigned short)v0[e];
                Vt[(d0 + 8 + e) * 72 + key] = (unsigned short)v1[e];
            }
        }
        __syncthreads();

        float bl[4][4];
#pragma unroll
        for (int kc = 0; kc < 4; kc++)
#pragma unroll
            for (int r = 0; r < 4; r++) {
                int q = q0 + wq * 16 + 4 * g + r;
                bl[kc][r] = bias_h[(size_t)q * 576 + kt + kc * 16 + l16];
            }

        f32x4 sc[4] = {};
        __builtin_amdgcn_s_setprio(1);
#pragma unroll
        for (int kc = 0; kc < 4; kc++) {
            bf16x8 kf0 = *(const bf16x8*)&Ks[(kc * 16 + l16) * 72 + g * 8];
            bf16x8 kf1 = *(const bf16x8*)&Ks[(kc * 16 + l16) * 72 + 32 + g * 8];
            sc[kc] = __builtin_amdgcn_mfma_f32_16x16x32_bf16(qf0, kf0, sc[kc], 0, 0, 0);
            sc[kc] = __builtin_amdgcn_mfma_f32_16x16x32_bf16(qf1, kf1, sc[kc], 0, 0, 0);
        }
        __builtin_amdgcn_s_setprio(0);

        float sv[4][4], mt[4] = {-1e30f, -1e30f, -1e30f, -1e30f};
#pragma unroll
        for (int kc = 0; kc < 4; kc++)
#pragma unroll
            for (int r = 0; r < 4; r++) {
                float s = sc[kc][r] * scale + bl[kc][r];
                sv[kc][r] = s;
                mt[r] = fmaxf(mt[r], s);
            }
#pragma unroll
        for (int r = 0; r < 4; r++)
#pragma unroll
            for (int m = 1; m < 16; m <<= 1) mt[r] = fmaxf(mt[r], __shfl_xor(mt[r], m));

        float sf[4];
#pragma unroll
        for (int r = 0; r < 4; r++) {
            float mn = fmaxf(m_r[r], mt[r]);
            sf[r] = __expf(m_r[r] - mn);
            m_r[r] = mn;
        }
        float rs[4] = {0.f, 0.f, 0.f, 0.f};
#pragma unroll
        for (int kc = 0; kc < 4; kc++)
#pragma unroll
            for (int r = 0; r < 4; r++) {
                float p = __expf(sv[kc][r] - m_r[r]);
                rs[r] += p;
                Ps[wq][(4 * g + r) * 72 + kc * 16 + l16] = f2bf_bits(p);
            }
#pragma unroll
        for (int r = 0; r < 4; r++) {
#pragma unroll
            for (int m = 1; m < 16; m <<= 1) rs[r] += __shfl_xor(rs[r], m);
            l_r[r] = l_r[r] * sf[r] + rs[r];
        }
#pragma unroll
        for (int dt = 0; dt < 4; dt++)
#pragma unroll
            for (int r = 0; r < 4; r++) oa[dt][r] *= sf[r];

        asm volatile("s_waitcnt lgkmcnt(0)" ::: "memory");

        __builtin_amdgcn_s_setprio(1);
#pragma unroll
        for (int s = 0; s < 2; s++) {
            bf16x8 pf = *(const bf16x8*)&Ps[wq][l16 * 72 + s * 32 + g * 8];
#pragma unroll
            for (int dt = 0; dt < 4; dt++) {
                bf16x8 vf = *(const bf16x8*)&Vt[(dt * 16 + l16) * 72 + s * 32 + g * 8];
                oa[dt] = __builtin_amdgcn_mfma_f32_16x16x32_bf16(pf, vf, oa[dt], 0, 0, 0);
            }
        }
        __builtin_amdgcn_s_setprio(0);
        __syncthreads();
    }

#pragma unroll
    for (int dt = 0; dt < 4; dt++)
#pragma unroll
        for (int r = 0; r < 4; r++) {
            int q = q0 + wq * 16 + 4 * g + r;
            float v = oa[dt][r] / l_r[r];
            o[(size_t)(bb * 576 + q) * 768 + h * 64 + dt * 16 + l16] = f2bf_bits(v);
        }
}

// ---------------- mean pool over 576 tokens (bf16 in) ----------------
__global__ __launch_bounds__(256) void pool_kernel(const __hip_bfloat16* __restrict__ tok,
                                                   float* __restrict__ pooled)
{
    int d = blockIdx.x * 256 + threadIdx.x;
    int b = blockIdx.y;
    float s = 0.0f;
    for (int n = 0; n < 576; n++) s += __bfloat162float(tok[(size_t)(b * 576 + n) * 768 + d]);
    pooled[b * 768 + d] = s * (1.0f / 576.0f);
}

// ---------------- classifier head ----------------
__global__ __launch_bounds__(256) void head_kernel(const float* __restrict__ lnp,
                                                   const float* __restrict__ w,
                                                   const float* __restrict__ bh,
                                                   float* __restrict__ out)
{
    int c = blockIdx.x * 256 + threadIdx.x;
    int b = blockIdx.y;
    if (c >= 1000) return;
    float s = bh[c];
    for (int d = 0; d < 768; d++) s += lnp[b * 768 + d] * w[(size_t)d * 1000 + c];
    out[b * 1000 + c] = s;
}

extern "C" void kernel_launch(void* const* d_in, const int* in_sizes, int n_in,
                              void* d_out, int out_size, void* d_ws, size_t ws_size,
                              hipStream_t stream)
{
    const float* x = (const float*)d_in[0];
    const float* patch_w = (const float*)d_in[1];
    const float* patch_b = (const float*)d_in[2];
    const float* ln1_g = (const float*)d_in[3];
    const float* ln1_b = (const float*)d_in[4];
    const float* w_qkv = (const float*)d_in[5];
    const float* bias_att = (const float*)d_in[6];
    const float* w_out = (const float*)d_in[7];
    const float* ln2_g = (const float*)d_in[8];
    const float* ln2_b = (const float*)d_in[9];
    const float* w1 = (const float*)d_in[10];
    const float* b1 = (const float*)d_in[11];
    const float* w2 = (const float*)d_in[12];
    const float* b2 = (const float*)d_in[13];
    const float* lnh_g = (const float*)d_in[14];
    const float* lnh_b = (const float*)d_in[15];
    const float* w_head = (const float*)d_in[16];
    const float* b_head = (const float*)d_in[17];
    float* out = (float*)d_out;

    char* ws = (char*)d_ws;
    __hip_bfloat16* tok = (__hip_bfloat16*)(ws + 0);             // 4608*768 bf16
    __hip_bfloat16* qkv_bf = (__hip_bfloat16*)(ws + 14155776);   // 4608*2304 bf16
    float* coef = (float*)(ws + 35389440);                       // 4*10752 f32
    float2* stats = (float2*)(ws + 35561856);                    // 4608 float2
    float* part = (float*)(ws + 35717120);                       // 4*24*2*5376 f32 = 4,128,768 B
    float* pooled = (float*)(ws + 56623104);
    float* pooledln = (float*)(ws + 56647680);
    __hip_bfloat16* patches = (__hip_bfloat16*)(ws + 56672256);  // 4608*1536 bf16
    __hip_bfloat16* lw = patches;                                // per-layer weights (fallback path)
    __hip_bfloat16* o_bf = (__hip_bfloat16*)(ws + 77905920);
    __hip_bfloat16* hid_bf = (__hip_bfloat16*)(ws + 84983808);
    __hip_bfloat16* wbuf = (__hip_bfloat16*)(ws + 113295360);    // patch weight 768*1536 bf16
    __hip_bfloat16* lwAll = (__hip_bfloat16*)(ws + 118013952);   // all-layers weights (gated)
    const bool useAll = ws_size >= (size_t)118013952 + 56623104;

    // patch embedding + one-shot weight prep
    patchify_kernel<<<3456, 256, 0, stream>>>(x, (unsigned short*)patches);
    convT_patch_kernel<<<dim3(24, 48), 256, 0, stream>>>(patch_w, wbuf);
    gemm_bt_kernel<true, false, false><<<432, 256, 0, stream>>>(
        patches, wbuf, patch_b, nullptr, tok, 4608, 768, 1536, 6);

    if (useAll) {
        convT4all_kernel<<<27648, 256, 0, stream>>>(
            w_qkv, w_out, w1, w2, ln1_g, ln1_b, ln2_g, ln2_b, lwAll, part);
        lnreduce_kernel<<<dim3(21, 4), 256, 0, stream>>>(part, b1, coef, 0);
    }

    for (int l = 0; l < 4; l++) {
        __hip_bfloat16* lwl = useAll ? lwAll + (size_t)l * 7077888 : lw;
        const float* cf = coef + (size_t)l * 10752;
        if (!useAll) {
            convT4_kernel<<<6912, 256, 0, stream>>>(
                w_qkv + (size_t)l * 768 * 2304, w_out + (size_t)l * 768 * 768,
                w1 + (size_t)l * 768 * 3072, w2 + (size_t)l * 3072 * 768,
                ln1_g + l * 768, ln1_b + l * 768, ln2_g + l * 768, ln2_b + l * 768, lw, part);
            lnreduce_kernel<<<dim3(21, 1), 256, 0, stream>>>(part, b1, coef, l);
        }
        // attn sub-block (LN1 folded into qkv GEMM)
        stats_kernel<<<1152, 256, 0, stream>>>(tok, stats);
        gemm_8ph_kernel<false><<<162, 512, 0, stream>>>(
            tok, lwl, stats, cf, cf + 2304, qkv_bf, 4608, 2304, 768, 9);
        attn_kernel<<<864, 256, 0, stream>>>(
            qkv_bf, bias_att + (size_t)l * 12 * 576 * 576, (unsigned short*)o_bf);
        gemm_bt_kernel<false, true, false><<<432, 256, 0, stream>>>(
            o_bf, lwl + 1769472, nullptr, tok, tok, 4608, 768, 768, 6);
        // mlp sub-block (LN2 + b1 folded into up GEMM)
        stats_kernel<<<1152, 256, 0, stream>>>(tok, stats);
        gemm_8ph_kernel<true><<<216, 512, 0, stream>>>(
            tok, lwl + 2359296, stats, cf + 4608, cf + 4608 + 3072, hid_bf, 4608, 3072, 768, 12);
        gemm_bt_kernel<true, true, false><<<432, 256, 0, stream>>>(
            hid_bf, lwl + 4718592, b2 + l * 768, tok, tok, 4608, 768, 3072, 6);
    }

    pool_kernel<<<dim3(3, 8), 256, 0, stream>>>(tok, pooled);
    lnf_kernel<<<8, 192, 0, stream>>>(pooled, lnh_g, lnh_b, pooledln);
    head_kernel<<<dim3(4, 8), 256, 0, stream>>>(pooledln, w_head, b_head, out);
}